// Round 5
// baseline (233.427 us; speedup 1.0000x reference)
//
#include <hip/hip_runtime.h>

typedef _Float16 f16;
typedef _Float16 half8 __attribute__((ext_vector_type(8)));
typedef _Float16 half4v __attribute__((ext_vector_type(4)));
typedef float floatx4 __attribute__((ext_vector_type(4)));

#define B_ 64
#define T_ 256
#define C_ 384
#define H_ 6
#define D_ 64
#define NROWS (B_*T_)

typedef __attribute__((address_space(3))) void lds_void_t;
typedef const __attribute__((address_space(1))) void gvoid_t;

__device__ __forceinline__ void g2lds16(const void* g, void* l) {
  __builtin_amdgcn_global_load_lds((gvoid_t*)g, (lds_void_t*)l, 16, 0, 0);
}

// ---------------- fused prep (weight repack fp32->f16 B^T) + LN1 ----------------
// blocks 0..107: Wq/Wk/Wv head-tiles; 108..215: Wp/W1/W2 64x64 tiles; 216: biases;
// 217..4312: LN1 rows (4 rows/block).
__global__ __launch_bounds__(256) void prep_ln_kernel(
    const float* __restrict__ Wq, const float* __restrict__ Wk, const float* __restrict__ Wv,
    const float* __restrict__ bq, const float* __restrict__ bk, const float* __restrict__ bv,
    const float* __restrict__ Wp, const float* __restrict__ W1, const float* __restrict__ W2,
    f16* __restrict__ Wqkv_t, f16* __restrict__ Wp_t, f16* __restrict__ W1_t, f16* __restrict__ W2_t,
    float* __restrict__ bqkv,
    const float* __restrict__ x, const float* __restrict__ gamma, const float* __restrict__ beta,
    f16* __restrict__ hout)
{
  const int bid = blockIdx.x;
  const int tid = threadIdx.x;
  if (bid >= 217) {
    // ---- LN1: wave per row
    int row = (bid - 217) * 4 + (tid >> 6);
    int lane = tid & 63;
    const float* xr = x + (size_t)row * 384;
    float v[6]; float s = 0.f;
#pragma unroll
    for (int j = 0; j < 6; j++) { v[j] = xr[lane + 64*j]; s += v[j]; }
#pragma unroll
    for (int m = 1; m < 64; m <<= 1) s += __shfl_xor(s, m);
    float mu = s * (1.f/384.f);
    float var = 0.f;
#pragma unroll
    for (int j = 0; j < 6; j++) { float d = v[j]-mu; var += d*d; }
#pragma unroll
    for (int m = 1; m < 64; m <<= 1) var += __shfl_xor(var, m);
    float rs = rsqrtf(var * (1.f/384.f) + 1e-5f);
    f16* orow = hout + (size_t)row*384;
#pragma unroll
    for (int j = 0; j < 6; j++) {
      int col = lane + 64*j;
      orow[col] = (f16)((v[j]-mu)*rs*gamma[col] + beta[col]);
    }
    return;
  }
  if (bid == 216) {
    for (int i = tid; i < 1152; i += 256) {
      float v;
      if (i < 384)      v = bq[i];
      else if (i < 768) v = bk[i - 384];
      else              v = bv[i - 768];
      bqkv[i] = v;
    }
    return;
  }
  __shared__ __align__(16) float tile[64*68];
  const float* src; int srcStride; f16* dst;
  if (bid < 108) {
    int mat = bid / 36, rem = bid - mat*36;
    int h = rem / 6, kt = rem - h*6;
    const float* W = (mat == 0) ? Wq : (mat == 1) ? Wk : Wv;
    src = W + (size_t)(h*384 + kt*64)*64;
    srcStride = 64;
    dst = Wqkv_t + (size_t)(mat*384 + h*64)*384 + kt*64;
  } else {
    int b2 = bid - 108;
    int mat = b2 / 36, rem = b2 - mat*36;
    int kt = rem / 6, ct = rem - kt*6;
    const float* W = (mat == 0) ? Wp : (mat == 1) ? W1 : W2;
    src = W + (size_t)(kt*64)*384 + ct*64;
    srcStride = 384;
    f16* O = (mat == 0) ? Wp_t : (mat == 1) ? W1_t : W2_t;
    dst = O + (size_t)(ct*64)*384 + kt*64;
  }
#pragma unroll
  for (int i = 0; i < 4; i++) {
    int idx = i*256 + tid;
    int r = idx >> 4, c4 = idx & 15;
    float4 v = *(const float4*)(src + (size_t)r*srcStride + c4*4);
    *(float4*)(&tile[r*68 + c4*4]) = v;
  }
  __syncthreads();
#pragma unroll
  for (int i = 0; i < 4; i++) {
    int idx = i*256 + tid;
    int d = idx >> 4, k4 = idx & 15;
    half4v o;
#pragma unroll
    for (int j = 0; j < 4; j++) o[j] = (f16)tile[(k4*4 + j)*68 + d];
    *(half4v*)(dst + (size_t)d*384 + k4*4) = o;
  }
}

// ---------------- layernorm: fp32 in -> f16 out, wave per row ----------------
__global__ __launch_bounds__(256) void ln_kernel(const float* __restrict__ x,
    const float* __restrict__ gamma, const float* __restrict__ beta, f16* __restrict__ out)
{
  int row = blockIdx.x * 4 + (threadIdx.x >> 6);
  int lane = threadIdx.x & 63;
  const float* xr = x + (size_t)row * 384;
  float v[6]; float s = 0.f;
#pragma unroll
  for (int j = 0; j < 6; j++) { v[j] = xr[lane + 64*j]; s += v[j]; }
#pragma unroll
  for (int m = 1; m < 64; m <<= 1) s += __shfl_xor(s, m);
  float mu = s * (1.f/384.f);
  float var = 0.f;
#pragma unroll
  for (int j = 0; j < 6; j++) { float d = v[j]-mu; var += d*d; }
#pragma unroll
  for (int m = 1; m < 64; m <<= 1) var += __shfl_xor(var, m);
  float rs = rsqrtf(var * (1.f/384.f) + 1e-5f);
  f16* orow = out + (size_t)row*384;
#pragma unroll
  for (int j = 0; j < 6; j++) {
    int col = lane + 64*j;
    orow[col] = (f16)((v[j]-mu)*rs*gamma[col] + beta[col]);
  }
}

// ---------------- GEMM: C[M,N] = A[M,384] @ Bt[N,384]^T + bias ----------------
// R2-proven 128x128 tile, BK=32 ping-pong: issue next step's global_load_lds
// BEFORE this step's ds_read+MFMA; single __syncthreads per step.
// MODE 0: f16 out.  MODE 1: f16 relu out.  MODE 2: f32 out + fp32 residual.
template<int MODE>
__global__ __launch_bounds__(256) void gemm_kernel(
    const f16* __restrict__ A, const f16* __restrict__ Bt,
    const float* __restrict__ bias, const float* __restrict__ res,
    void* __restrict__ outp, int ldo)
{
  __shared__ __align__(16) f16 As[2][128*32];
  __shared__ __align__(16) f16 Bs[2][128*32];
  const int tid = threadIdx.x;
  const int lane = tid & 63, w = tid >> 6;
  const int wm = w >> 1, wn = w & 1;
  const int q = lane >> 4, c15 = lane & 15;
  const long row0 = (long)blockIdx.x * 128;
  const long col0 = (long)blockIdx.y * 128;
  floatx4 acc[4][4] = {};

  const int c0 = tid,        r0c = c0 >> 2, p0 = c0 & 3, g0 = p0 ^ ((r0c >> 1) & 3);
  const int c1 = 256 + tid,  r1c = c1 >> 2, p1 = c1 & 3, g1 = p1 ^ ((r1c >> 1) & 3);
  const f16* Arow0 = A  + (row0 + r0c)*384 + g0*8;
  const f16* Arow1 = A  + (row0 + r1c)*384 + g1*8;
  const f16* Brow0 = Bt + (col0 + r0c)*384 + g0*8;
  const f16* Brow1 = Bt + (col0 + r1c)*384 + g1*8;
  // wave-uniform LDS bases (+ lane*16 implicit)
  const int dof0 = (w*64)*8, dof1 = (256 + w*64)*8;

#define GEMM_STAGE(buf, kk) do { \
    g2lds16(Arow0 + (kk), &As[buf][dof0]); \
    g2lds16(Arow1 + (kk), &As[buf][dof1]); \
    g2lds16(Brow0 + (kk), &Bs[buf][dof0]); \
    g2lds16(Brow1 + (kk), &Bs[buf][dof1]); \
  } while (0)

#define GEMM_COMPUTE(buf) do { \
    half8 af[4], bf[4]; \
    _Pragma("unroll") \
    for (int mi = 0; mi < 4; mi++) { \
      int r = wm*64 + mi*16 + c15; \
      int ph = q ^ ((r >> 1) & 3); \
      af[mi] = *(const half8*)(&As[buf][r*32 + ph*8]); \
    } \
    _Pragma("unroll") \
    for (int ni = 0; ni < 4; ni++) { \
      int r = wn*64 + ni*16 + c15; \
      int ph = q ^ ((r >> 1) & 3); \
      bf[ni] = *(const half8*)(&Bs[buf][r*32 + ph*8]); \
    } \
    _Pragma("unroll") \
    for (int mi = 0; mi < 4; mi++) \
      _Pragma("unroll") \
      for (int ni = 0; ni < 4; ni++) \
        acc[mi][ni] = __builtin_amdgcn_mfma_f32_16x16x32_f16(af[mi], bf[ni], acc[mi][ni], 0, 0, 0); \
  } while (0)

  GEMM_STAGE(0, 0);
  __syncthreads();
#pragma unroll
  for (int t = 0; t < 11; ++t) {
    GEMM_STAGE((t + 1) & 1, (t + 1) * 32);
    GEMM_COMPUTE(t & 1);
    __syncthreads();
  }
  GEMM_COMPUTE(1);

#undef GEMM_STAGE
#undef GEMM_COMPUTE

#pragma unroll
  for (int ni = 0; ni < 4; ni++) {
    long col = col0 + wn*64 + ni*16 + c15;
    float bv = bias[col];
#pragma unroll
    for (int mi = 0; mi < 4; mi++) {
      long rowb = row0 + wm*64 + mi*16 + q*4;
#pragma unroll
      for (int r = 0; r < 4; r++) {
        float vo = acc[mi][ni][r] + bv;
        if (MODE == 1) vo = vo > 0.f ? vo : 0.f;
        long o = (rowb + r) * (long)ldo + col;
        if (MODE == 2) {
          ((float*)outp)[o] = vo + res[o];
        } else {
          ((f16*)outp)[o] = (f16)vo;
        }
      }
    }
  }
}

// ---------------- fused causal attention ----------------
// R5: 2 q-tiles per block. 768 blocks x 512 threads (8 waves); wave w owns
// q-row-tile qt2*128 + w*16. K/V staged ONCE per 128-q-row pair (staging
// traffic -30%); LDS = 32KB kvbuf + 16KB Pbuf = 48KB -> 3 blocks/CU = 1536
// threads/CU (75% cap, was 50%), and 768 blocks = exactly one resident
// generation (no multi-round tail). Per-wave structure (swizzles, mask,
// softmax, PV) identical to the R4-proven kernel.
__global__ __launch_bounds__(512, 6) void attn_kernel(const f16* __restrict__ qkv,
                                                      f16* __restrict__ attn_out)
{
  __shared__ __align__(16) char kvbuf[32768];
  __shared__ __align__(16) f16 Pbuf[8][16*64];
  f16* Ks = (f16*)kvbuf;
  unsigned int* vTw = (unsigned int*)kvbuf;
  f16* vT = (f16*)kvbuf;

  const int tid = threadIdx.x;
  const int bid = blockIdx.x;
  const int bh = bid >> 1, qt2 = bid & 1;     // qt2: lower/upper 128 q-rows
  const int b = bh / 6, h = bh - b*6;
  const f16* qp = qkv + (size_t)b*256*1152 + h*64;
  const f16* kp = qp + 384;
  const f16* vp = qp + 768;
  const int lane = tid & 63, w = tid >> 6;
  const int q = lane >> 4, c15 = lane & 15;

  // --- stage K into LDS (async), swizzled via pre-swizzled global source.
  // keys = (qt2+1)*128; chunks = keys*8; 512 threads -> iters = (qt2+1)*2.
  {
    const int iters = (qt2 + 1) * 2;
    for (int i = 0; i < iters; i++) {
      int pc = i*512 + tid;
      int rc = pc >> 3, p = pc & 7;
      int c = p ^ (rc & 7);
      g2lds16(kp + (size_t)rc*1152 + c*8, (char*)kvbuf + (size_t)(i*512 + w*64)*16);
    }
  }

  // --- Q fragments: issued before the barrier so latency overlaps K staging
  const int nmax = qt2*8 + w;
  const int trow0 = qt2*128 + w*16;
  const f16* qrow = qp + (size_t)(trow0 + c15)*1152 + q*8;
  half8 aq0 = *(const half8*)(qrow);
  half8 aq1 = *(const half8*)(qrow + 32);

  __syncthreads();

  // --- QK^T
  floatx4 sacc[16];
  __builtin_amdgcn_s_setprio(1);
#pragma unroll
  for (int ni = 0; ni < 16; ni++) {
    if (ni <= nmax) {
      int s = ni*16 + c15;
      const f16* kr = Ks + s*64;
      int p0 = q ^ (s & 7);
      half8 b0 = *(const half8*)(kr + p0*8);
      half8 b1 = *(const half8*)(kr + (p0 ^ 4)*8);
      floatx4 a = {0.f, 0.f, 0.f, 0.f};
      a = __builtin_amdgcn_mfma_f32_16x16x32_f16(aq0, b0, a, 0, 0, 0);
      a = __builtin_amdgcn_mfma_f32_16x16x32_f16(aq1, b1, a, 0, 0, 0);
      sacc[ni] = a;
    }
  }
  __builtin_amdgcn_s_setprio(0);
  __syncthreads();   // all waves done reading K -> kvbuf reusable for vT

  // --- V loads to registers (issued now; consumed after softmax so the
  //     global latency hides under the softmax VALU work below).
  // pairs = keys/2 = (qt2+1)*64; 512 threads -> iters = qt2+1.
  half8 va[2], vb[2];
#pragma unroll
  for (int i = 0; i < 2; i++) {
    if (i <= qt2) {
      int idx = i*512 + tid;
      int sp = idx >> 3, part = idx & 7;
      const f16* v0 = vp + (size_t)(2*sp)*1152 + part*8;
      va[i] = *(const half8*)(v0);
      vb[i] = *(const half8*)(v0 + 1152);
    }
  }

  // --- softmax (scale, causal mask, max, exp, sum) — pure VALU/shfl
  const float scale = 0.051031036307982884f;
  float mx[4] = {-1e30f, -1e30f, -1e30f, -1e30f};
#pragma unroll
  for (int ni = 0; ni < 16; ni++) {
    if (ni < nmax) {
#pragma unroll
      for (int r = 0; r < 4; r++) { float v = sacc[ni][r]*scale; sacc[ni][r] = v; mx[r] = fmaxf(mx[r], v); }
    } else if (ni == nmax) {
#pragma unroll
      for (int r = 0; r < 4; r++) {
        float v = sacc[ni][r]*scale;
        v = (c15 <= q*4 + r) ? v : -1e30f;
        sacc[ni][r] = v; mx[r] = fmaxf(mx[r], v);
      }
    }
  }
#pragma unroll
  for (int r = 0; r < 4; r++) {
    mx[r] = fmaxf(mx[r], __shfl_xor(mx[r], 1));
    mx[r] = fmaxf(mx[r], __shfl_xor(mx[r], 2));
    mx[r] = fmaxf(mx[r], __shfl_xor(mx[r], 4));
    mx[r] = fmaxf(mx[r], __shfl_xor(mx[r], 8));
  }
  float l[4] = {0.f, 0.f, 0.f, 0.f};
#pragma unroll
  for (int ni = 0; ni < 16; ni++) {
    if (ni <= nmax) {
#pragma unroll
      for (int r = 0; r < 4; r++) { float p = __expf(sacc[ni][r] - mx[r]); sacc[ni][r] = p; l[r] += p; }
    }
  }
#pragma unroll
  for (int r = 0; r < 4; r++) {
    l[r] += __shfl_xor(l[r], 1);
    l[r] += __shfl_xor(l[r], 2);
    l[r] += __shfl_xor(l[r], 4);
    l[r] += __shfl_xor(l[r], 8);
  }

  // --- transpose-write V into vT (paired-row f16 packs, swizzled)
#pragma unroll
  for (int i = 0; i < 2; i++) {
    if (i <= qt2) {
      int idx = i*512 + tid;
      int sp = idx >> 3, part = idx & 7;
      int csp = sp >> 2, spw = sp & 3;
#pragma unroll
      for (int j = 0; j < 8; j++) {
        int d = part*8 + j;
        int swz = (d & 15) ^ (d >> 3);
        int p = csp ^ swz;
        union { struct { f16 lo, hi; } s; unsigned int u; } pk;
        pk.s.lo = va[i][j]; pk.s.hi = vb[i][j];
        vTw[d*128 + p*4 + spw] = pk.u;
      }
    }
  }
  __syncthreads();

  // --- PV: 4 chunks of 64 keys, per-wave 16x64 Pbuf
  f16* Pw = &Pbuf[w][0];
  floatx4 oacc[4] = {};
  const int kend_w = (nmax + 1) * 16;
#pragma unroll
  for (int ch = 0; ch < 4; ch++) {
    if (ch*64 < kend_w) {
#pragma unroll
      for (int nl = 0; nl < 4; nl++) {
        int ni = ch*4 + nl;
        if (ni <= nmax) {
#pragma unroll
          for (int r = 0; r < 4; r++) {
            int row = q*4 + r;
            int colp = nl*16 + c15;
            int php = (colp >> 3) ^ (row & 7);
            Pw[row*64 + php*8 + (colp & 7)] = (f16)sacc[ni][r];
          }
        } else if (ni == nmax + 1) {
#pragma unroll
          for (int r = 0; r < 4; r++) {
            int row = q*4 + r;
            int colp = nl*16 + c15;
            int php = (colp >> 3) ^ (row & 7);
            Pw[row*64 + php*8 + (colp & 7)] = (f16)0.f;
          }
        }
      }
      __builtin_amdgcn_s_setprio(1);
#pragma unroll
      for (int kc = 0; kc < 2; kc++) {
        if (ch*64 + kc*32 < kend_w) {
          int pc = (kc*4 + q) ^ (c15 & 7);
          half8 ap = *(const half8*)(Pw + c15*64 + pc*8);
          int sc = ch*8 + kc*4 + q;
#pragma unroll
          for (int nt = 0; nt < 4; nt++) {
            int d = nt*16 + c15;
            int swz = (d & 15) ^ (d >> 3);
            half8 bv = *(const half8*)(vT + d*256 + ((sc ^ swz))*8);
            oacc[nt] = __builtin_amdgcn_mfma_f32_16x16x32_f16(ap, bv, oacc[nt], 0, 0, 0);
          }
        }
      }
      __builtin_amdgcn_s_setprio(0);
    }
  }

  float rl[4];
#pragma unroll
  for (int r = 0; r < 4; r++) rl[r] = 1.0f / l[r];
#pragma unroll
  for (int nt = 0; nt < 4; nt++) {
#pragma unroll
    for (int r = 0; r < 4; r++) {
      int t = trow0 + q*4 + r;
      int d = nt*16 + c15;
      attn_out[(size_t)(b*256 + t)*384 + h*64 + d] = (f16)(oacc[nt][r] * rl[r]);
    }
  }
}

extern "C" void kernel_launch(void* const* d_in, const int* in_sizes, int n_in,
                              void* d_out, int out_size, void* d_ws, size_t ws_size,
                              hipStream_t stream) {
  const float* x   = (const float*)d_in[0];
  const float* Wq  = (const float*)d_in[1];
  const float* bq  = (const float*)d_in[2];
  const float* Wk  = (const float*)d_in[3];
  const float* bk  = (const float*)d_in[4];
  const float* Wv  = (const float*)d_in[5];
  const float* bv  = (const float*)d_in[6];
  const float* Wp  = (const float*)d_in[7];
  const float* bp  = (const float*)d_in[8];
  const float* W1  = (const float*)d_in[9];
  const float* b1  = (const float*)d_in[10];
  const float* W2  = (const float*)d_in[11];
  const float* b2  = (const float*)d_in[12];
  const float* g1  = (const float*)d_in[13];
  const float* be1 = (const float*)d_in[14];
  const float* g2  = (const float*)d_in[15];
  const float* be2 = (const float*)d_in[16];

  char* ws = (char*)d_ws;
  size_t off = 0;
  auto alloc = [&](size_t bytes) -> void* {
    void* p = ws + off;
    off += (bytes + 255) & ~(size_t)255;
    return p;
  };
  f16*   Wqkv_t = (f16*)  alloc(1152*384*sizeof(f16));
  f16*   Wp_t   = (f16*)  alloc(384*384*sizeof(f16));
  f16*   W1_t   = (f16*)  alloc(384*384*sizeof(f16));
  f16*   W2_t   = (f16*)  alloc(384*384*sizeof(f16));
  float* bqkv   = (float*)alloc(1152*sizeof(float));
  f16*   h      = (f16*)  alloc((size_t)NROWS*384*sizeof(f16));
  f16*   qkv    = (f16*)  alloc((size_t)NROWS*1152*sizeof(f16));
  f16*   attnb  = (f16*)  alloc((size_t)NROWS*384*sizeof(f16));
  float* x2     = (float*)alloc((size_t)NROWS*384*sizeof(float));
  f16*   h2     = (f16*)  alloc((size_t)NROWS*384*sizeof(f16));
  f16*   mid    = (f16*)  alloc((size_t)NROWS*384*sizeof(f16));

  // 1. fused: weight repack + LN1
  prep_ln_kernel<<<217 + NROWS/4, 256, 0, stream>>>(Wq, Wk, Wv, bq, bk, bv, Wp, W1, W2,
                                                    Wqkv_t, Wp_t, W1_t, W2_t, bqkv,
                                                    x, g1, be1, h);
  // 2. QKV: qkv[16384,1152] = h @ Wqkv + bqkv (f16 out)
  gemm_kernel<0><<<dim3(128, 9), 256, 0, stream>>>(h, Wqkv_t, bqkv, nullptr, qkv, 1152);
  // 3. attention: 768 blocks x 512 threads (2 q-tiles per block)
  attn_kernel<<<B_*H_*2, 512, 0, stream>>>(qkv, attnb);
  // 4. proj + residual: x2 = x + attn @ Wp + bp (f32 out)
  gemm_kernel<2><<<dim3(128, 3), 256, 0, stream>>>(attnb, Wp_t, bp, x, x2, 384);
  // 5. LN2: x2 -> h2 (f16)
  ln_kernel<<<NROWS/4, 256, 0, stream>>>(x2, g2, be2, h2);
  // 6. FF1: mid = relu(h2 @ W1 + b1) (f16 out)
  gemm_kernel<1><<<dim3(128, 3), 256, 0, stream>>>(h2, W1_t, b1, nullptr, mid, 384);
  // 7. FF2: out = x2 + mid @ W2 + b2 (f32 out)
  gemm_kernel<2><<<dim3(128, 3), 256, 0, stream>>>(mid, W2_t, b2, x2, (float*)d_out, 384);
}

// Round 6
// 199.585 us; speedup vs baseline: 1.1696x; 1.1696x over previous
//
#include <hip/hip_runtime.h>

typedef _Float16 f16;
typedef _Float16 half8 __attribute__((ext_vector_type(8)));
typedef _Float16 half4v __attribute__((ext_vector_type(4)));
typedef float floatx4 __attribute__((ext_vector_type(4)));

#define B_ 64
#define T_ 256
#define C_ 384
#define H_ 6
#define D_ 64
#define NROWS (B_*T_)

typedef __attribute__((address_space(3))) void lds_void_t;
typedef const __attribute__((address_space(1))) void gvoid_t;

__device__ __forceinline__ void g2lds16(const void* g, void* l) {
  __builtin_amdgcn_global_load_lds((gvoid_t*)g, (lds_void_t*)l, 16, 0, 0);
}

// ---------------- fused prep (weight repack fp32->f16 B^T) + LN1 ----------------
// blocks 0..107: Wq/Wk/Wv head-tiles; 108..215: Wp/W1/W2 64x64 tiles; 216: biases;
// 217..4312: LN1 rows (4 rows/block).
__global__ __launch_bounds__(256) void prep_ln_kernel(
    const float* __restrict__ Wq, const float* __restrict__ Wk, const float* __restrict__ Wv,
    const float* __restrict__ bq, const float* __restrict__ bk, const float* __restrict__ bv,
    const float* __restrict__ Wp, const float* __restrict__ W1, const float* __restrict__ W2,
    f16* __restrict__ Wqkv_t, f16* __restrict__ Wp_t, f16* __restrict__ W1_t, f16* __restrict__ W2_t,
    float* __restrict__ bqkv,
    const float* __restrict__ x, const float* __restrict__ gamma, const float* __restrict__ beta,
    f16* __restrict__ hout)
{
  const int bid = blockIdx.x;
  const int tid = threadIdx.x;
  if (bid >= 217) {
    // ---- LN1: wave per row
    int row = (bid - 217) * 4 + (tid >> 6);
    int lane = tid & 63;
    const float* xr = x + (size_t)row * 384;
    float v[6]; float s = 0.f;
#pragma unroll
    for (int j = 0; j < 6; j++) { v[j] = xr[lane + 64*j]; s += v[j]; }
#pragma unroll
    for (int m = 1; m < 64; m <<= 1) s += __shfl_xor(s, m);
    float mu = s * (1.f/384.f);
    float var = 0.f;
#pragma unroll
    for (int j = 0; j < 6; j++) { float d = v[j]-mu; var += d*d; }
#pragma unroll
    for (int m = 1; m < 64; m <<= 1) var += __shfl_xor(var, m);
    float rs = rsqrtf(var * (1.f/384.f) + 1e-5f);
    f16* orow = hout + (size_t)row*384;
#pragma unroll
    for (int j = 0; j < 6; j++) {
      int col = lane + 64*j;
      orow[col] = (f16)((v[j]-mu)*rs*gamma[col] + beta[col]);
    }
    return;
  }
  if (bid == 216) {
    for (int i = tid; i < 1152; i += 256) {
      float v;
      if (i < 384)      v = bq[i];
      else if (i < 768) v = bk[i - 384];
      else              v = bv[i - 768];
      bqkv[i] = v;
    }
    return;
  }
  __shared__ __align__(16) float tile[64*68];
  const float* src; int srcStride; f16* dst;
  if (bid < 108) {
    int mat = bid / 36, rem = bid - mat*36;
    int h = rem / 6, kt = rem - h*6;
    const float* W = (mat == 0) ? Wq : (mat == 1) ? Wk : Wv;
    src = W + (size_t)(h*384 + kt*64)*64;
    srcStride = 64;
    dst = Wqkv_t + (size_t)(mat*384 + h*64)*384 + kt*64;
  } else {
    int b2 = bid - 108;
    int mat = b2 / 36, rem = b2 - mat*36;
    int kt = rem / 6, ct = rem - kt*6;
    const float* W = (mat == 0) ? Wp : (mat == 1) ? W1 : W2;
    src = W + (size_t)(kt*64)*384 + ct*64;
    srcStride = 384;
    f16* O = (mat == 0) ? Wp_t : (mat == 1) ? W1_t : W2_t;
    dst = O + (size_t)(ct*64)*384 + kt*64;
  }
#pragma unroll
  for (int i = 0; i < 4; i++) {
    int idx = i*256 + tid;
    int r = idx >> 4, c4 = idx & 15;
    float4 v = *(const float4*)(src + (size_t)r*srcStride + c4*4);
    *(float4*)(&tile[r*68 + c4*4]) = v;
  }
  __syncthreads();
#pragma unroll
  for (int i = 0; i < 4; i++) {
    int idx = i*256 + tid;
    int d = idx >> 4, k4 = idx & 15;
    half4v o;
#pragma unroll
    for (int j = 0; j < 4; j++) o[j] = (f16)tile[(k4*4 + j)*68 + d];
    *(half4v*)(dst + (size_t)d*384 + k4*4) = o;
  }
}

// ---------------- layernorm: fp32 in -> f16 out, wave per row ----------------
__global__ __launch_bounds__(256) void ln_kernel(const float* __restrict__ x,
    const float* __restrict__ gamma, const float* __restrict__ beta, f16* __restrict__ out)
{
  int row = blockIdx.x * 4 + (threadIdx.x >> 6);
  int lane = threadIdx.x & 63;
  const float* xr = x + (size_t)row * 384;
  float v[6]; float s = 0.f;
#pragma unroll
  for (int j = 0; j < 6; j++) { v[j] = xr[lane + 64*j]; s += v[j]; }
#pragma unroll
  for (int m = 1; m < 64; m <<= 1) s += __shfl_xor(s, m);
  float mu = s * (1.f/384.f);
  float var = 0.f;
#pragma unroll
  for (int j = 0; j < 6; j++) { float d = v[j]-mu; var += d*d; }
#pragma unroll
  for (int m = 1; m < 64; m <<= 1) var += __shfl_xor(var, m);
  float rs = rsqrtf(var * (1.f/384.f) + 1e-5f);
  f16* orow = out + (size_t)row*384;
#pragma unroll
  for (int j = 0; j < 6; j++) {
    int col = lane + 64*j;
    orow[col] = (f16)((v[j]-mu)*rs*gamma[col] + beta[col]);
  }
}

// ---------------- GEMM: C[M,N] = A[M,384] @ Bt[N,384]^T + bias, BK=64 (R1-best) ----
// MODE 0: f16 out.  MODE 1: f16 relu out.  MODE 2: f32 out + fp32 residual.
template<int MODE>
__global__ __launch_bounds__(256) void gemm_kernel(
    const f16* __restrict__ A, const f16* __restrict__ Bt,
    const float* __restrict__ bias, const float* __restrict__ res,
    void* __restrict__ outp, int ldo)
{
  __shared__ __align__(16) f16 As[2][128*32];
  __shared__ __align__(16) f16 Bs[2][128*32];
  const int tid = threadIdx.x;
  const int lane = tid & 63, w = tid >> 6;
  const int wm = w >> 1, wn = w & 1;
  const int q = lane >> 4, c15 = lane & 15;
  const long row0 = (long)blockIdx.x * 128;
  const long col0 = (long)blockIdx.y * 128;
  floatx4 acc[4][4] = {};

  const int c0 = tid,        r0c = c0 >> 2, p0 = c0 & 3, g0 = p0 ^ ((r0c >> 1) & 3);
  const int c1 = 256 + tid,  r1c = c1 >> 2, p1 = c1 & 3, g1 = p1 ^ ((r1c >> 1) & 3);
  const f16* Arow0 = A  + (row0 + r0c)*384 + g0*8;
  const f16* Arow1 = A  + (row0 + r1c)*384 + g1*8;
  const f16* Brow0 = Bt + (col0 + r0c)*384 + g0*8;
  const f16* Brow1 = Bt + (col0 + r1c)*384 + g1*8;
  // wave-uniform LDS bases (+ lane*16 implicit)
  const int dof0 = (w*64)*8, dof1 = (256 + w*64)*8;

  for (int k0 = 0; k0 < 384; k0 += 64) {
#pragma unroll
    for (int hf = 0; hf < 2; hf++) {
      int kk = k0 + hf*32;
      g2lds16(Arow0 + kk, &As[hf][dof0]);
      g2lds16(Arow1 + kk, &As[hf][dof1]);
      g2lds16(Brow0 + kk, &Bs[hf][dof0]);
      g2lds16(Brow1 + kk, &Bs[hf][dof1]);
    }
    __syncthreads();
#pragma unroll
    for (int hf = 0; hf < 2; hf++) {
      half8 af[4], bf[4];
#pragma unroll
      for (int mi = 0; mi < 4; mi++) {
        int r = wm*64 + mi*16 + c15;
        int ph = q ^ ((r >> 1) & 3);
        af[mi] = *(const half8*)(&As[hf][r*32 + ph*8]);
      }
#pragma unroll
      for (int ni = 0; ni < 4; ni++) {
        int r = wn*64 + ni*16 + c15;
        int ph = q ^ ((r >> 1) & 3);
        bf[ni] = *(const half8*)(&Bs[hf][r*32 + ph*8]);
      }
#pragma unroll
      for (int mi = 0; mi < 4; mi++)
#pragma unroll
        for (int ni = 0; ni < 4; ni++)
          acc[mi][ni] = __builtin_amdgcn_mfma_f32_16x16x32_f16(af[mi], bf[ni], acc[mi][ni], 0, 0, 0);
    }
    __syncthreads();
  }

#pragma unroll
  for (int ni = 0; ni < 4; ni++) {
    long col = col0 + wn*64 + ni*16 + c15;
    float bv = bias[col];
#pragma unroll
    for (int mi = 0; mi < 4; mi++) {
      long rowb = row0 + wm*64 + mi*16 + q*4;
#pragma unroll
      for (int r = 0; r < 4; r++) {
        float vo = acc[mi][ni][r] + bv;
        if (MODE == 1) vo = vo > 0.f ? vo : 0.f;
        long o = (rowb + r) * (long)ldo + col;
        if (MODE == 2) {
          ((float*)outp)[o] = vo + res[o];
        } else {
          ((f16*)outp)[o] = (f16)vo;
        }
      }
    }
  }
}

// ---------------- fused causal attention ----------------
// R6: R5's 2-q-tile structure with the launch-bounds bug fixed.
// 768 blocks x 512 threads (8 waves); wave w owns q-row-tile qt2*128 + w*16.
// K/V staged once per 128-q-row pair; LDS = 48KB -> 3 blocks/CU (24 waves/CU,
// LDS-limited) and 768 blocks = exactly one resident generation.
// __launch_bounds__(512, 2): VGPR cap 256 -- R5's (512,6) forced VGPR=40 and
// spilled ~100MB to scratch (WRITE_SIZE 104MB, dur 60us). Occupancy is set by
// LDS, not the bound, so (512,2) costs nothing and removes the spill.
__global__ __launch_bounds__(512, 2) void attn_kernel(const f16* __restrict__ qkv,
                                                      f16* __restrict__ attn_out)
{
  __shared__ __align__(16) char kvbuf[32768];
  __shared__ __align__(16) f16 Pbuf[8][16*64];
  f16* Ks = (f16*)kvbuf;
  unsigned int* vTw = (unsigned int*)kvbuf;
  f16* vT = (f16*)kvbuf;

  const int tid = threadIdx.x;
  const int bid = blockIdx.x;
  const int bh = bid >> 1, qt2 = bid & 1;     // qt2: lower/upper 128 q-rows
  const int b = bh / 6, h = bh - b*6;
  const f16* qp = qkv + (size_t)b*256*1152 + h*64;
  const f16* kp = qp + 384;
  const f16* vp = qp + 768;
  const int lane = tid & 63, w = tid >> 6;
  const int q = lane >> 4, c15 = lane & 15;

  // --- stage K into LDS (async), swizzled via pre-swizzled global source.
  // keys = (qt2+1)*128; chunks = keys*8; 512 threads -> iters = (qt2+1)*2.
  {
    const int iters = (qt2 + 1) * 2;
    for (int i = 0; i < iters; i++) {
      int pc = i*512 + tid;
      int rc = pc >> 3, p = pc & 7;
      int c = p ^ (rc & 7);
      g2lds16(kp + (size_t)rc*1152 + c*8, (char*)kvbuf + (size_t)(i*512 + w*64)*16);
    }
  }

  // --- Q fragments: issued before the barrier so latency overlaps K staging
  const int nmax = qt2*8 + w;
  const int trow0 = qt2*128 + w*16;
  const f16* qrow = qp + (size_t)(trow0 + c15)*1152 + q*8;
  half8 aq0 = *(const half8*)(qrow);
  half8 aq1 = *(const half8*)(qrow + 32);

  __syncthreads();

  // --- QK^T
  floatx4 sacc[16];
  __builtin_amdgcn_s_setprio(1);
#pragma unroll
  for (int ni = 0; ni < 16; ni++) {
    if (ni <= nmax) {
      int s = ni*16 + c15;
      const f16* kr = Ks + s*64;
      int p0 = q ^ (s & 7);
      half8 b0 = *(const half8*)(kr + p0*8);
      half8 b1 = *(const half8*)(kr + (p0 ^ 4)*8);
      floatx4 a = {0.f, 0.f, 0.f, 0.f};
      a = __builtin_amdgcn_mfma_f32_16x16x32_f16(aq0, b0, a, 0, 0, 0);
      a = __builtin_amdgcn_mfma_f32_16x16x32_f16(aq1, b1, a, 0, 0, 0);
      sacc[ni] = a;
    }
  }
  __builtin_amdgcn_s_setprio(0);
  __syncthreads();   // all waves done reading K -> kvbuf reusable for vT

  // --- V loads to registers (issued now; consumed after softmax so the
  //     global latency hides under the softmax VALU work below).
  // pairs = keys/2 = (qt2+1)*64; 512 threads -> iters = qt2+1.
  half8 va[2], vb[2];
#pragma unroll
  for (int i = 0; i < 2; i++) {
    if (i <= qt2) {
      int idx = i*512 + tid;
      int sp = idx >> 3, part = idx & 7;
      const f16* v0 = vp + (size_t)(2*sp)*1152 + part*8;
      va[i] = *(const half8*)(v0);
      vb[i] = *(const half8*)(v0 + 1152);
    }
  }

  // --- softmax (scale, causal mask, max, exp, sum) — pure VALU/shfl
  const float scale = 0.051031036307982884f;
  float mx[4] = {-1e30f, -1e30f, -1e30f, -1e30f};
#pragma unroll
  for (int ni = 0; ni < 16; ni++) {
    if (ni < nmax) {
#pragma unroll
      for (int r = 0; r < 4; r++) { float v = sacc[ni][r]*scale; sacc[ni][r] = v; mx[r] = fmaxf(mx[r], v); }
    } else if (ni == nmax) {
#pragma unroll
      for (int r = 0; r < 4; r++) {
        float v = sacc[ni][r]*scale;
        v = (c15 <= q*4 + r) ? v : -1e30f;
        sacc[ni][r] = v; mx[r] = fmaxf(mx[r], v);
      }
    }
  }
#pragma unroll
  for (int r = 0; r < 4; r++) {
    mx[r] = fmaxf(mx[r], __shfl_xor(mx[r], 1));
    mx[r] = fmaxf(mx[r], __shfl_xor(mx[r], 2));
    mx[r] = fmaxf(mx[r], __shfl_xor(mx[r], 4));
    mx[r] = fmaxf(mx[r], __shfl_xor(mx[r], 8));
  }
  float l[4] = {0.f, 0.f, 0.f, 0.f};
#pragma unroll
  for (int ni = 0; ni < 16; ni++) {
    if (ni <= nmax) {
#pragma unroll
      for (int r = 0; r < 4; r++) { float p = __expf(sacc[ni][r] - mx[r]); sacc[ni][r] = p; l[r] += p; }
    }
  }
#pragma unroll
  for (int r = 0; r < 4; r++) {
    l[r] += __shfl_xor(l[r], 1);
    l[r] += __shfl_xor(l[r], 2);
    l[r] += __shfl_xor(l[r], 4);
    l[r] += __shfl_xor(l[r], 8);
  }

  // --- transpose-write V into vT (paired-row f16 packs, swizzled)
#pragma unroll
  for (int i = 0; i < 2; i++) {
    if (i <= qt2) {
      int idx = i*512 + tid;
      int sp = idx >> 3, part = idx & 7;
      int csp = sp >> 2, spw = sp & 3;
#pragma unroll
      for (int j = 0; j < 8; j++) {
        int d = part*8 + j;
        int swz = (d & 15) ^ (d >> 3);
        int p = csp ^ swz;
        union { struct { f16 lo, hi; } s; unsigned int u; } pk;
        pk.s.lo = va[i][j]; pk.s.hi = vb[i][j];
        vTw[d*128 + p*4 + spw] = pk.u;
      }
    }
  }
  __syncthreads();

  // --- PV: 4 chunks of 64 keys, per-wave 16x64 Pbuf
  f16* Pw = &Pbuf[w][0];
  floatx4 oacc[4] = {};
  const int kend_w = (nmax + 1) * 16;
#pragma unroll
  for (int ch = 0; ch < 4; ch++) {
    if (ch*64 < kend_w) {
#pragma unroll
      for (int nl = 0; nl < 4; nl++) {
        int ni = ch*4 + nl;
        if (ni <= nmax) {
#pragma unroll
          for (int r = 0; r < 4; r++) {
            int row = q*4 + r;
            int colp = nl*16 + c15;
            int php = (colp >> 3) ^ (row & 7);
            Pw[row*64 + php*8 + (colp & 7)] = (f16)sacc[ni][r];
          }
        } else if (ni == nmax + 1) {
#pragma unroll
          for (int r = 0; r < 4; r++) {
            int row = q*4 + r;
            int colp = nl*16 + c15;
            int php = (colp >> 3) ^ (row & 7);
            Pw[row*64 + php*8 + (colp & 7)] = (f16)0.f;
          }
        }
      }
      __builtin_amdgcn_s_setprio(1);
#pragma unroll
      for (int kc = 0; kc < 2; kc++) {
        if (ch*64 + kc*32 < kend_w) {
          int pc = (kc*4 + q) ^ (c15 & 7);
          half8 ap = *(const half8*)(Pw + c15*64 + pc*8);
          int sc = ch*8 + kc*4 + q;
#pragma unroll
          for (int nt = 0; nt < 4; nt++) {
            int d = nt*16 + c15;
            int swz = (d & 15) ^ (d >> 3);
            half8 bv = *(const half8*)(vT + d*256 + ((sc ^ swz))*8);
            oacc[nt] = __builtin_amdgcn_mfma_f32_16x16x32_f16(ap, bv, oacc[nt], 0, 0, 0);
          }
        }
      }
      __builtin_amdgcn_s_setprio(0);
    }
  }

  float rl[4];
#pragma unroll
  for (int r = 0; r < 4; r++) rl[r] = 1.0f / l[r];
#pragma unroll
  for (int nt = 0; nt < 4; nt++) {
#pragma unroll
    for (int r = 0; r < 4; r++) {
      int t = trow0 + q*4 + r;
      int d = nt*16 + c15;
      attn_out[(size_t)(b*256 + t)*384 + h*64 + d] = (f16)(oacc[nt][r] * rl[r]);
    }
  }
}

extern "C" void kernel_launch(void* const* d_in, const int* in_sizes, int n_in,
                              void* d_out, int out_size, void* d_ws, size_t ws_size,
                              hipStream_t stream) {
  const float* x   = (const float*)d_in[0];
  const float* Wq  = (const float*)d_in[1];
  const float* bq  = (const float*)d_in[2];
  const float* Wk  = (const float*)d_in[3];
  const float* bk  = (const float*)d_in[4];
  const float* Wv  = (const float*)d_in[5];
  const float* bv  = (const float*)d_in[6];
  const float* Wp  = (const float*)d_in[7];
  const float* bp  = (const float*)d_in[8];
  const float* W1  = (const float*)d_in[9];
  const float* b1  = (const float*)d_in[10];
  const float* W2  = (const float*)d_in[11];
  const float* b2  = (const float*)d_in[12];
  const float* g1  = (const float*)d_in[13];
  const float* be1 = (const float*)d_in[14];
  const float* g2  = (const float*)d_in[15];
  const float* be2 = (const float*)d_in[16];

  char* ws = (char*)d_ws;
  size_t off = 0;
  auto alloc = [&](size_t bytes) -> void* {
    void* p = ws + off;
    off += (bytes + 255) & ~(size_t)255;
    return p;
  };
  f16*   Wqkv_t = (f16*)  alloc(1152*384*sizeof(f16));
  f16*   Wp_t   = (f16*)  alloc(384*384*sizeof(f16));
  f16*   W1_t   = (f16*)  alloc(384*384*sizeof(f16));
  f16*   W2_t   = (f16*)  alloc(384*384*sizeof(f16));
  float* bqkv   = (float*)alloc(1152*sizeof(float));
  f16*   h      = (f16*)  alloc((size_t)NROWS*384*sizeof(f16));
  f16*   qkv    = (f16*)  alloc((size_t)NROWS*1152*sizeof(f16));
  f16*   attnb  = (f16*)  alloc((size_t)NROWS*384*sizeof(f16));
  float* x2     = (float*)alloc((size_t)NROWS*384*sizeof(float));
  f16*   h2     = (f16*)  alloc((size_t)NROWS*384*sizeof(f16));
  f16*   mid    = (f16*)  alloc((size_t)NROWS*384*sizeof(f16));

  // 1. fused: weight repack + LN1
  prep_ln_kernel<<<217 + NROWS/4, 256, 0, stream>>>(Wq, Wk, Wv, bq, bk, bv, Wp, W1, W2,
                                                    Wqkv_t, Wp_t, W1_t, W2_t, bqkv,
                                                    x, g1, be1, h);
  // 2. QKV: qkv[16384,1152] = h @ Wqkv + bqkv (f16 out)
  gemm_kernel<0><<<dim3(128, 9), 256, 0, stream>>>(h, Wqkv_t, bqkv, nullptr, qkv, 1152);
  // 3. attention: 768 blocks x 512 threads (2 q-tiles per block)
  attn_kernel<<<B_*H_*2, 512, 0, stream>>>(qkv, attnb);
  // 4. proj + residual: x2 = x + attn @ Wp + bp (f32 out)
  gemm_kernel<2><<<dim3(128, 3), 256, 0, stream>>>(attnb, Wp_t, bp, x, x2, 384);
  // 5. LN2: x2 -> h2 (f16)
  ln_kernel<<<NROWS/4, 256, 0, stream>>>(x2, g2, be2, h2);
  // 6. FF1: mid = relu(h2 @ W1 + b1) (f16 out)
  gemm_kernel<1><<<dim3(128, 3), 256, 0, stream>>>(h2, W1_t, b1, nullptr, mid, 384);
  // 7. FF2: out = x2 + mid @ W2 + b2 (f32 out)
  gemm_kernel<2><<<dim3(128, 3), 256, 0, stream>>>(mid, W2_t, b2, x2, (float*)d_out, 384);
}

// Round 7
// 189.690 us; speedup vs baseline: 1.2306x; 1.0522x over previous
//
#include <hip/hip_runtime.h>

typedef _Float16 f16;
typedef _Float16 half8 __attribute__((ext_vector_type(8)));
typedef _Float16 half4v __attribute__((ext_vector_type(4)));
typedef float floatx4 __attribute__((ext_vector_type(4)));

#define B_ 64
#define T_ 256
#define C_ 384
#define H_ 6
#define D_ 64
#define NROWS (B_*T_)

typedef __attribute__((address_space(3))) void lds_void_t;
typedef const __attribute__((address_space(1))) void gvoid_t;

__device__ __forceinline__ void g2lds16(const void* g, void* l) {
  __builtin_amdgcn_global_load_lds((gvoid_t*)g, (lds_void_t*)l, 16, 0, 0);
}

// ---------------- fused prep (weight repack fp32->f16 B^T) + LN1 ----------------
__global__ __launch_bounds__(256) void prep_ln_kernel(
    const float* __restrict__ Wq, const float* __restrict__ Wk, const float* __restrict__ Wv,
    const float* __restrict__ bq, const float* __restrict__ bk, const float* __restrict__ bv,
    const float* __restrict__ Wp, const float* __restrict__ W1, const float* __restrict__ W2,
    f16* __restrict__ Wqkv_t, f16* __restrict__ Wp_t, f16* __restrict__ W1_t, f16* __restrict__ W2_t,
    float* __restrict__ bqkv,
    const float* __restrict__ x, const float* __restrict__ gamma, const float* __restrict__ beta,
    f16* __restrict__ hout)
{
  const int bid = blockIdx.x;
  const int tid = threadIdx.x;
  if (bid >= 217) {
    // ---- LN1: wave per row
    int row = (bid - 217) * 4 + (tid >> 6);
    int lane = tid & 63;
    const float* xr = x + (size_t)row * 384;
    float v[6]; float s = 0.f;
#pragma unroll
    for (int j = 0; j < 6; j++) { v[j] = xr[lane + 64*j]; s += v[j]; }
#pragma unroll
    for (int m = 1; m < 64; m <<= 1) s += __shfl_xor(s, m);
    float mu = s * (1.f/384.f);
    float var = 0.f;
#pragma unroll
    for (int j = 0; j < 6; j++) { float d = v[j]-mu; var += d*d; }
#pragma unroll
    for (int m = 1; m < 64; m <<= 1) var += __shfl_xor(var, m);
    float rs = rsqrtf(var * (1.f/384.f) + 1e-5f);
    f16* orow = hout + (size_t)row*384;
#pragma unroll
    for (int j = 0; j < 6; j++) {
      int col = lane + 64*j;
      orow[col] = (f16)((v[j]-mu)*rs*gamma[col] + beta[col]);
    }
    return;
  }
  if (bid == 216) {
    for (int i = tid; i < 1152; i += 256) {
      float v;
      if (i < 384)      v = bq[i];
      else if (i < 768) v = bk[i - 384];
      else              v = bv[i - 768];
      bqkv[i] = v;
    }
    return;
  }
  __shared__ __align__(16) float tile[64*68];
  const float* src; int srcStride; f16* dst;
  if (bid < 108) {
    int mat = bid / 36, rem = bid - mat*36;
    int h = rem / 6, kt = rem - h*6;
    const float* W = (mat == 0) ? Wq : (mat == 1) ? Wk : Wv;
    src = W + (size_t)(h*384 + kt*64)*64;
    srcStride = 64;
    dst = Wqkv_t + (size_t)(mat*384 + h*64)*384 + kt*64;
  } else {
    int b2 = bid - 108;
    int mat = b2 / 36, rem = b2 - mat*36;
    int kt = rem / 6, ct = rem - kt*6;
    const float* W = (mat == 0) ? Wp : (mat == 1) ? W1 : W2;
    src = W + (size_t)(kt*64)*384 + ct*64;
    srcStride = 384;
    f16* O = (mat == 0) ? Wp_t : (mat == 1) ? W1_t : W2_t;
    dst = O + (size_t)(ct*64)*384 + kt*64;
  }
#pragma unroll
  for (int i = 0; i < 4; i++) {
    int idx = i*256 + tid;
    int r = idx >> 4, c4 = idx & 15;
    float4 v = *(const float4*)(src + (size_t)r*srcStride + c4*4);
    *(float4*)(&tile[r*68 + c4*4]) = v;
  }
  __syncthreads();
#pragma unroll
  for (int i = 0; i < 4; i++) {
    int idx = i*256 + tid;
    int d = idx >> 4, k4 = idx & 15;
    half4v o;
#pragma unroll
    for (int j = 0; j < 4; j++) o[j] = (f16)tile[(k4*4 + j)*68 + d];
    *(half4v*)(dst + (size_t)d*384 + k4*4) = o;
  }
}

// ---------------- GEMM (QKV): C[M,1152] = A[M,384] @ Bt^T + bias, f16 out ----------------
// R1-proven 128x128 tile, BK=64.
__global__ __launch_bounds__(256) void gemm_qkv_kernel(
    const f16* __restrict__ A, const f16* __restrict__ Bt,
    const float* __restrict__ bias, f16* __restrict__ outp, int ldo)
{
  __shared__ __align__(16) f16 As[2][128*32];
  __shared__ __align__(16) f16 Bs[2][128*32];
  const int tid = threadIdx.x;
  const int lane = tid & 63, w = tid >> 6;
  const int wm = w >> 1, wn = w & 1;
  const int q = lane >> 4, c15 = lane & 15;
  const long row0 = (long)blockIdx.x * 128;
  const long col0 = (long)blockIdx.y * 128;
  floatx4 acc[4][4] = {};

  const int c0 = tid,        r0c = c0 >> 2, p0 = c0 & 3, g0 = p0 ^ ((r0c >> 1) & 3);
  const int c1 = 256 + tid,  r1c = c1 >> 2, p1 = c1 & 3, g1 = p1 ^ ((r1c >> 1) & 3);
  const f16* Arow0 = A  + (row0 + r0c)*384 + g0*8;
  const f16* Arow1 = A  + (row0 + r1c)*384 + g1*8;
  const f16* Brow0 = Bt + (col0 + r0c)*384 + g0*8;
  const f16* Brow1 = Bt + (col0 + r1c)*384 + g1*8;
  const int dof0 = (w*64)*8, dof1 = (256 + w*64)*8;

  for (int k0 = 0; k0 < 384; k0 += 64) {
#pragma unroll
    for (int hf = 0; hf < 2; hf++) {
      int kk = k0 + hf*32;
      g2lds16(Arow0 + kk, &As[hf][dof0]);
      g2lds16(Arow1 + kk, &As[hf][dof1]);
      g2lds16(Brow0 + kk, &Bs[hf][dof0]);
      g2lds16(Brow1 + kk, &Bs[hf][dof1]);
    }
    __syncthreads();
#pragma unroll
    for (int hf = 0; hf < 2; hf++) {
      half8 af[4], bf[4];
#pragma unroll
      for (int mi = 0; mi < 4; mi++) {
        int r = wm*64 + mi*16 + c15;
        int ph = q ^ ((r >> 1) & 3);
        af[mi] = *(const half8*)(&As[hf][r*32 + ph*8]);
      }
#pragma unroll
      for (int ni = 0; ni < 4; ni++) {
        int r = wn*64 + ni*16 + c15;
        int ph = q ^ ((r >> 1) & 3);
        bf[ni] = *(const half8*)(&Bs[hf][r*32 + ph*8]);
      }
#pragma unroll
      for (int mi = 0; mi < 4; mi++)
#pragma unroll
        for (int ni = 0; ni < 4; ni++)
          acc[mi][ni] = __builtin_amdgcn_mfma_f32_16x16x32_f16(af[mi], bf[ni], acc[mi][ni], 0, 0, 0);
    }
    __syncthreads();
  }

#pragma unroll
  for (int ni = 0; ni < 4; ni++) {
    long col = col0 + wn*64 + ni*16 + c15;
    float bv = bias[col];
#pragma unroll
    for (int mi = 0; mi < 4; mi++) {
      long rowb = row0 + wm*64 + mi*16 + q*4;
#pragma unroll
      for (int r = 0; r < 4; r++) {
        float vo = acc[mi][ni][r] + bv;
        outp[(rowb + r) * (long)ldo + col] = (f16)vo;
      }
    }
  }
}

// ---------------- fused causal attention (R6-proven) ----------------
__global__ __launch_bounds__(512, 2) void attn_kernel(const f16* __restrict__ qkv,
                                                      f16* __restrict__ attn_out)
{
  __shared__ __align__(16) char kvbuf[32768];
  __shared__ __align__(16) f16 Pbuf[8][16*64];
  f16* Ks = (f16*)kvbuf;
  unsigned int* vTw = (unsigned int*)kvbuf;
  f16* vT = (f16*)kvbuf;

  const int tid = threadIdx.x;
  const int bid = blockIdx.x;
  const int bh = bid >> 1, qt2 = bid & 1;
  const int b = bh / 6, h = bh - b*6;
  const f16* qp = qkv + (size_t)b*256*1152 + h*64;
  const f16* kp = qp + 384;
  const f16* vp = qp + 768;
  const int lane = tid & 63, w = tid >> 6;
  const int q = lane >> 4, c15 = lane & 15;

  {
    const int iters = (qt2 + 1) * 2;
    for (int i = 0; i < iters; i++) {
      int pc = i*512 + tid;
      int rc = pc >> 3, p = pc & 7;
      int c = p ^ (rc & 7);
      g2lds16(kp + (size_t)rc*1152 + c*8, (char*)kvbuf + (size_t)(i*512 + w*64)*16);
    }
  }

  const int nmax = qt2*8 + w;
  const int trow0 = qt2*128 + w*16;
  const f16* qrow = qp + (size_t)(trow0 + c15)*1152 + q*8;
  half8 aq0 = *(const half8*)(qrow);
  half8 aq1 = *(const half8*)(qrow + 32);

  __syncthreads();

  floatx4 sacc[16];
  __builtin_amdgcn_s_setprio(1);
#pragma unroll
  for (int ni = 0; ni < 16; ni++) {
    if (ni <= nmax) {
      int s = ni*16 + c15;
      const f16* kr = Ks + s*64;
      int p0 = q ^ (s & 7);
      half8 b0 = *(const half8*)(kr + p0*8);
      half8 b1 = *(const half8*)(kr + (p0 ^ 4)*8);
      floatx4 a = {0.f, 0.f, 0.f, 0.f};
      a = __builtin_amdgcn_mfma_f32_16x16x32_f16(aq0, b0, a, 0, 0, 0);
      a = __builtin_amdgcn_mfma_f32_16x16x32_f16(aq1, b1, a, 0, 0, 0);
      sacc[ni] = a;
    }
  }
  __builtin_amdgcn_s_setprio(0);
  __syncthreads();

  half8 va[2], vb[2];
#pragma unroll
  for (int i = 0; i < 2; i++) {
    if (i <= qt2) {
      int idx = i*512 + tid;
      int sp = idx >> 3, part = idx & 7;
      const f16* v0 = vp + (size_t)(2*sp)*1152 + part*8;
      va[i] = *(const half8*)(v0);
      vb[i] = *(const half8*)(v0 + 1152);
    }
  }

  const float scale = 0.051031036307982884f;
  float mx[4] = {-1e30f, -1e30f, -1e30f, -1e30f};
#pragma unroll
  for (int ni = 0; ni < 16; ni++) {
    if (ni < nmax) {
#pragma unroll
      for (int r = 0; r < 4; r++) { float v = sacc[ni][r]*scale; sacc[ni][r] = v; mx[r] = fmaxf(mx[r], v); }
    } else if (ni == nmax) {
#pragma unroll
      for (int r = 0; r < 4; r++) {
        float v = sacc[ni][r]*scale;
        v = (c15 <= q*4 + r) ? v : -1e30f;
        sacc[ni][r] = v; mx[r] = fmaxf(mx[r], v);
      }
    }
  }
#pragma unroll
  for (int r = 0; r < 4; r++) {
    mx[r] = fmaxf(mx[r], __shfl_xor(mx[r], 1));
    mx[r] = fmaxf(mx[r], __shfl_xor(mx[r], 2));
    mx[r] = fmaxf(mx[r], __shfl_xor(mx[r], 4));
    mx[r] = fmaxf(mx[r], __shfl_xor(mx[r], 8));
  }
  float l[4] = {0.f, 0.f, 0.f, 0.f};
#pragma unroll
  for (int ni = 0; ni < 16; ni++) {
    if (ni <= nmax) {
#pragma unroll
      for (int r = 0; r < 4; r++) { float p = __expf(sacc[ni][r] - mx[r]); sacc[ni][r] = p; l[r] += p; }
    }
  }
#pragma unroll
  for (int r = 0; r < 4; r++) {
    l[r] += __shfl_xor(l[r], 1);
    l[r] += __shfl_xor(l[r], 2);
    l[r] += __shfl_xor(l[r], 4);
    l[r] += __shfl_xor(l[r], 8);
  }

#pragma unroll
  for (int i = 0; i < 2; i++) {
    if (i <= qt2) {
      int idx = i*512 + tid;
      int sp = idx >> 3, part = idx & 7;
      int csp = sp >> 2, spw = sp & 3;
#pragma unroll
      for (int j = 0; j < 8; j++) {
        int d = part*8 + j;
        int swz = (d & 15) ^ (d >> 3);
        int p = csp ^ swz;
        union { struct { f16 lo, hi; } s; unsigned int u; } pk;
        pk.s.lo = va[i][j]; pk.s.hi = vb[i][j];
        vTw[d*128 + p*4 + spw] = pk.u;
      }
    }
  }
  __syncthreads();

  f16* Pw = &Pbuf[w][0];
  floatx4 oacc[4] = {};
  const int kend_w = (nmax + 1) * 16;
#pragma unroll
  for (int ch = 0; ch < 4; ch++) {
    if (ch*64 < kend_w) {
#pragma unroll
      for (int nl = 0; nl < 4; nl++) {
        int ni = ch*4 + nl;
        if (ni <= nmax) {
#pragma unroll
          for (int r = 0; r < 4; r++) {
            int row = q*4 + r;
            int colp = nl*16 + c15;
            int php = (colp >> 3) ^ (row & 7);
            Pw[row*64 + php*8 + (colp & 7)] = (f16)sacc[ni][r];
          }
        } else if (ni == nmax + 1) {
#pragma unroll
          for (int r = 0; r < 4; r++) {
            int row = q*4 + r;
            int colp = nl*16 + c15;
            int php = (colp >> 3) ^ (row & 7);
            Pw[row*64 + php*8 + (colp & 7)] = (f16)0.f;
          }
        }
      }
      __builtin_amdgcn_s_setprio(1);
#pragma unroll
      for (int kc = 0; kc < 2; kc++) {
        if (ch*64 + kc*32 < kend_w) {
          int pc = (kc*4 + q) ^ (c15 & 7);
          half8 ap = *(const half8*)(Pw + c15*64 + pc*8);
          int sc = ch*8 + kc*4 + q;
#pragma unroll
          for (int nt = 0; nt < 4; nt++) {
            int d = nt*16 + c15;
            int swz = (d & 15) ^ (d >> 3);
            half8 bv = *(const half8*)(vT + d*256 + ((sc ^ swz))*8);
            oacc[nt] = __builtin_amdgcn_mfma_f32_16x16x32_f16(ap, bv, oacc[nt], 0, 0, 0);
          }
        }
      }
      __builtin_amdgcn_s_setprio(0);
    }
  }

  float rl[4];
#pragma unroll
  for (int r = 0; r < 4; r++) rl[r] = 1.0f / l[r];
#pragma unroll
  for (int nt = 0; nt < 4; nt++) {
#pragma unroll
    for (int r = 0; r < 4; r++) {
      int t = trow0 + q*4 + r;
      int d = nt*16 + c15;
      attn_out[(size_t)(b*256 + t)*384 + h*64 + d] = (f16)(oacc[nt][r] * rl[r]);
    }
  }
}

// ---------------- fused tail: proj + residual + LN2 + FF1 + FF2 ----------------
// The entire back half is row-block-local: a block owning 64 rows x all 384
// cols needs no cross-block data (LN2 per-row; FF1/FF2 row-local). One block
// per CU: grid 256, 512 threads = 8 waves (2 row x 4 col), wave = 32 rows x
// 96 cols, acc[2][6]. x2 lives in registers (vals); h2 and mid live in LDS in
// the staged-A swizzled layout (R3-refcheck-proven chaining) so phases read
// them directly as MFMA A-fragments. Kills x2/h2/mid HBM round-trips (~100MB)
// and 3 dispatch boundaries. LDS: 8+48+48+48+2.5 = ~154.5 KB (1 block/CU).
__global__ __launch_bounds__(512, 2) void tail_kernel(
    const f16* __restrict__ A, const f16* __restrict__ WpT,
    const f16* __restrict__ W1T, const f16* __restrict__ W2T,
    const float* __restrict__ bp, const float* __restrict__ b1, const float* __restrict__ b2,
    const float* __restrict__ x, const float* __restrict__ g2, const float* __restrict__ be2,
    float* __restrict__ out)
{
  __shared__ __align__(16) f16 As[2][64*32];
  __shared__ __align__(16) f16 Bs[2][384*32];
  __shared__ __align__(16) f16 h2b[12][64*32];
  __shared__ __align__(16) f16 midb[12][64*32];
  __shared__ float lnred[2][64][4];
  __shared__ float lnmv[2][64];

  const int tid = threadIdx.x;
  const int lane = tid & 63, w = tid >> 6;
  const int wm = w >> 2, wn = w & 3;
  const int q = lane >> 4, c15 = lane & 15;
  const long row0 = (long)blockIdx.x * 64;

  // ---- staging address precompute (16B chunks; XOR-swizzled k-groups) ----
  // A (64x32 per step = 256 chunks): waves 0-3
  const int cA = w*64 + lane;
  const int rA = cA >> 2, pA_ = cA & 3, gA = pA_ ^ ((rA >> 1) & 3);
  const f16* srcA = A + (row0 + rA)*384 + gA*8;
  // B (384x32 per step = 1536 chunks)
  // phase a passes: w>=4: chunks 0..255; all: 256..767; all: 768..1279; w<4: 1280..1535
  // phase b/c passes: all: 0..511, 512..1023, 1024..1535
  auto boff = [&](int cb) -> long {
    int rc = cb >> 2, p = cb & 3, g = p ^ ((rc >> 1) & 3);
    return (long)rc*384 + g*8;
  };
  const long offBa0 = boff((w >= 4 ? (w-4) : 0)*64 + lane);       // used if w>=4
  const long offBa1 = boff(256 + w*64 + lane);
  const long offBa2 = boff(768 + w*64 + lane);
  const long offBa3 = boff(1280 + (w < 4 ? w : 0)*64 + lane);     // used if w<4
  const long offBp0 = boff(w*64 + lane);
  const long offBp1 = boff(512 + w*64 + lane);
  const long offBp2 = boff(1024 + w*64 + lane);

  floatx4 acc[2][6] = {};

#define T_STAGE_A(buf, kk) do { \
    if (w < 4) { \
      g2lds16(srcA + (kk), &As[buf][(w*64)*8]); \
      g2lds16(WpT + offBa3 + (kk), &Bs[buf][(1280 + w*64)*8]); \
    } else { \
      g2lds16(WpT + offBa0 + (kk), &Bs[buf][((w-4)*64)*8]); \
    } \
    g2lds16(WpT + offBa1 + (kk), &Bs[buf][(256 + w*64)*8]); \
    g2lds16(WpT + offBa2 + (kk), &Bs[buf][(768 + w*64)*8]); \
  } while (0)

#define T_STAGE_B(buf, kk, BT) do { \
    g2lds16(BT + offBp0 + (kk), &Bs[buf][(w*64)*8]); \
    g2lds16(BT + offBp1 + (kk), &Bs[buf][(512 + w*64)*8]); \
    g2lds16(BT + offBp2 + (kk), &Bs[buf][(1024 + w*64)*8]); \
  } while (0)

#define T_COMP(ABUF_EXPR, buf) do { \
    half8 af[2], bf[6]; \
    _Pragma("unroll") \
    for (int mi = 0; mi < 2; mi++) { \
      int r = wm*32 + mi*16 + c15; \
      int ph = q ^ ((r >> 1) & 3); \
      af[mi] = *(const half8*)(&(ABUF_EXPR)[r*32 + ph*8]); \
    } \
    _Pragma("unroll") \
    for (int ni = 0; ni < 6; ni++) { \
      int rb = wn*96 + ni*16 + c15; \
      int phb = q ^ ((rb >> 1) & 3); \
      bf[ni] = *(const half8*)(&Bs[buf][rb*32 + phb*8]); \
    } \
    _Pragma("unroll") \
    for (int mi = 0; mi < 2; mi++) \
      _Pragma("unroll") \
      for (int ni = 0; ni < 6; ni++) \
        acc[mi][ni] = __builtin_amdgcn_mfma_f32_16x16x32_f16(af[mi], bf[ni], acc[mi][ni], 0, 0, 0); \
  } while (0)

  // ================= phase a: x2 = x + A@Wp + bp ; h2 = LN2(x2) =================
  T_STAGE_A(0, 0);
  __syncthreads();
#pragma unroll
  for (int t = 0; t < 11; ++t) {
    T_STAGE_A((t + 1) & 1, (t + 1) * 32);
    T_COMP(As[t & 1], t & 1);
    __syncthreads();
  }
  T_COMP(As[1], 1);

  float vals[2][6][4];
  {
    float colb[6], cg[6], cb2[6];
#pragma unroll
    for (int ni = 0; ni < 6; ni++) {
      int col = wn*96 + ni*16 + c15;
      colb[ni] = bp[col]; cg[ni] = g2[col]; cb2[ni] = be2[col];
    }
#pragma unroll
    for (int mi = 0; mi < 2; mi++) {
#pragma unroll
      for (int rr = 0; rr < 4; rr++) {
        long row = row0 + wm*32 + mi*16 + q*4 + rr;
#pragma unroll
        for (int ni = 0; ni < 6; ni++) {
          int col = wn*96 + ni*16 + c15;
          float v = acc[mi][ni][rr] + colb[ni] + x[row*384 + col];
          vals[mi][ni][rr] = v;
        }
      }
    }
    // per-row partial sums over this wave's 96 cols
#pragma unroll
    for (int mi = 0; mi < 2; mi++) {
#pragma unroll
      for (int rr = 0; rr < 4; rr++) {
        float s = 0.f, s2 = 0.f;
#pragma unroll
        for (int ni = 0; ni < 6; ni++) { float v = vals[mi][ni][rr]; s += v; s2 += v*v; }
        s  += __shfl_xor(s, 1);  s  += __shfl_xor(s, 2);  s  += __shfl_xor(s, 4);  s  += __shfl_xor(s, 8);
        s2 += __shfl_xor(s2, 1); s2 += __shfl_xor(s2, 2); s2 += __shfl_xor(s2, 4); s2 += __shfl_xor(s2, 8);
        if (c15 == 0) {
          int lr = wm*32 + mi*16 + q*4 + rr;
          lnred[0][lr][wn] = s;
          lnred[1][lr][wn] = s2;
        }
      }
    }
    __syncthreads();
    if (tid < 64) {
      float s = 0.f, s2 = 0.f;
#pragma unroll
      for (int j = 0; j < 4; j++) { s += lnred[0][tid][j]; s2 += lnred[1][tid][j]; }
      float mu = s * (1.f/384.f);
      float var = s2 * (1.f/384.f) - mu*mu;
      lnmv[0][tid] = mu;
      lnmv[1][tid] = rsqrtf(var + 1e-5f);
    }
    __syncthreads();
    // normalize -> h2b (staged-A swizzled layout)
#pragma unroll
    for (int mi = 0; mi < 2; mi++) {
#pragma unroll
      for (int rr = 0; rr < 4; rr++) {
        int lr = wm*32 + mi*16 + q*4 + rr;
        float mu = lnmv[0][lr], rs = lnmv[1][lr];
        int s_ = (lr >> 1) & 3;
#pragma unroll
        for (int ni = 0; ni < 6; ni++) {
          int cc = wn*96 + ni*16 + c15;
          float hv = (vals[mi][ni][rr] - mu)*rs*cg[ni] + cb2[ni];
          int chunk = cc >> 5, kk2 = cc & 31;
          int pos = ((kk2 >> 3) ^ s_)*8 + (kk2 & 7);
          h2b[chunk][lr*32 + pos] = (f16)hv;
        }
      }
    }
  }
  // stage first W1 tile while finishing epilogue; barrier publishes h2b + Bs[0]
  T_STAGE_B(0, 0, W1T);
  __syncthreads();

  // ================= phase b: mid = relu(h2 @ W1 + b1) =================
#pragma unroll
  for (int mi = 0; mi < 2; mi++)
#pragma unroll
    for (int ni = 0; ni < 6; ni++)
      acc[mi][ni] = floatx4{0.f, 0.f, 0.f, 0.f};
#pragma unroll
  for (int t = 0; t < 11; ++t) {
    T_STAGE_B((t + 1) & 1, (t + 1) * 32, W1T);
    T_COMP(h2b[t], t & 1);
    __syncthreads();
  }
  T_COMP(h2b[11], 1);

  {
    float colb[6];
#pragma unroll
    for (int ni = 0; ni < 6; ni++) colb[ni] = b1[wn*96 + ni*16 + c15];
#pragma unroll
    for (int mi = 0; mi < 2; mi++) {
#pragma unroll
      for (int rr = 0; rr < 4; rr++) {
        int lr = wm*32 + mi*16 + q*4 + rr;
        int s_ = (lr >> 1) & 3;
#pragma unroll
        for (int ni = 0; ni < 6; ni++) {
          int cc = wn*96 + ni*16 + c15;
          float v = acc[mi][ni][rr] + colb[ni];
          v = v > 0.f ? v : 0.f;
          int chunk = cc >> 5, kk2 = cc & 31;
          int pos = ((kk2 >> 3) ^ s_)*8 + (kk2 & 7);
          midb[chunk][lr*32 + pos] = (f16)v;
        }
      }
    }
  }
  T_STAGE_B(0, 0, W2T);
  __syncthreads();

  // ================= phase c: out = x2 + mid @ W2 + b2 =================
#pragma unroll
  for (int mi = 0; mi < 2; mi++)
#pragma unroll
    for (int ni = 0; ni < 6; ni++)
      acc[mi][ni] = floatx4{0.f, 0.f, 0.f, 0.f};
#pragma unroll
  for (int t = 0; t < 11; ++t) {
    T_STAGE_B((t + 1) & 1, (t + 1) * 32, W2T);
    T_COMP(midb[t], t & 1);
    __syncthreads();
  }
  T_COMP(midb[11], 1);

  {
    float colb[6];
#pragma unroll
    for (int ni = 0; ni < 6; ni++) colb[ni] = b2[wn*96 + ni*16 + c15];
#pragma unroll
    for (int mi = 0; mi < 2; mi++) {
#pragma unroll
      for (int rr = 0; rr < 4; rr++) {
        long row = row0 + wm*32 + mi*16 + q*4 + rr;
#pragma unroll
        for (int ni = 0; ni < 6; ni++) {
          int col = wn*96 + ni*16 + c15;
          out[row*384 + col] = acc[mi][ni][rr] + colb[ni] + vals[mi][ni][rr];
        }
      }
    }
  }

#undef T_STAGE_A
#undef T_STAGE_B
#undef T_COMP
}

extern "C" void kernel_launch(void* const* d_in, const int* in_sizes, int n_in,
                              void* d_out, int out_size, void* d_ws, size_t ws_size,
                              hipStream_t stream) {
  const float* x   = (const float*)d_in[0];
  const float* Wq  = (const float*)d_in[1];
  const float* bq  = (const float*)d_in[2];
  const float* Wk  = (const float*)d_in[3];
  const float* bk  = (const float*)d_in[4];
  const float* Wv  = (const float*)d_in[5];
  const float* bv  = (const float*)d_in[6];
  const float* Wp  = (const float*)d_in[7];
  const float* bp  = (const float*)d_in[8];
  const float* W1  = (const float*)d_in[9];
  const float* b1  = (const float*)d_in[10];
  const float* W2  = (const float*)d_in[11];
  const float* b2  = (const float*)d_in[12];
  const float* g1  = (const float*)d_in[13];
  const float* be1 = (const float*)d_in[14];
  const float* g2  = (const float*)d_in[15];
  const float* be2 = (const float*)d_in[16];

  char* ws = (char*)d_ws;
  size_t off = 0;
  auto alloc = [&](size_t bytes) -> void* {
    void* p = ws + off;
    off += (bytes + 255) & ~(size_t)255;
    return p;
  };
  f16*   Wqkv_t = (f16*)  alloc(1152*384*sizeof(f16));
  f16*   Wp_t   = (f16*)  alloc(384*384*sizeof(f16));
  f16*   W1_t   = (f16*)  alloc(384*384*sizeof(f16));
  f16*   W2_t   = (f16*)  alloc(384*384*sizeof(f16));
  float* bqkv   = (float*)alloc(1152*sizeof(float));
  f16*   h      = (f16*)  alloc((size_t)NROWS*384*sizeof(f16));
  f16*   qkv    = (f16*)  alloc((size_t)NROWS*1152*sizeof(f16));
  f16*   attnb  = (f16*)  alloc((size_t)NROWS*384*sizeof(f16));

  // 1. fused: weight repack + LN1
  prep_ln_kernel<<<217 + NROWS/4, 256, 0, stream>>>(Wq, Wk, Wv, bq, bk, bv, Wp, W1, W2,
                                                    Wqkv_t, Wp_t, W1_t, W2_t, bqkv,
                                                    x, g1, be1, h);
  // 2. QKV: qkv[16384,1152] = h @ Wqkv + bqkv (f16 out)
  gemm_qkv_kernel<<<dim3(128, 9), 256, 0, stream>>>(h, Wqkv_t, bqkv, qkv, 1152);
  // 3. attention: 768 blocks x 512 threads (2 q-tiles per block)
  attn_kernel<<<B_*H_*2, 512, 0, stream>>>(qkv, attnb);
  // 4. fused tail: proj + residual + LN2 + FF1 + FF2 (one block per CU)
  tail_kernel<<<NROWS/64, 512, 0, stream>>>(attnb, Wp_t, W1_t, W2_t, bp, b1, b2,
                                            x, g2, be2, (float*)d_out);
}

// Round 8
// 184.076 us; speedup vs baseline: 1.2681x; 1.0305x over previous
//
#include <hip/hip_runtime.h>

typedef _Float16 f16;
typedef _Float16 half8 __attribute__((ext_vector_type(8)));
typedef _Float16 half4v __attribute__((ext_vector_type(4)));
typedef float floatx4 __attribute__((ext_vector_type(4)));

#define B_ 64
#define T_ 256
#define C_ 384
#define H_ 6
#define D_ 64
#define NROWS (B_*T_)

typedef __attribute__((address_space(3))) void lds_void_t;
typedef const __attribute__((address_space(1))) void gvoid_t;

__device__ __forceinline__ void g2lds16(const void* g, void* l) {
  __builtin_amdgcn_global_load_lds((gvoid_t*)g, (lds_void_t*)l, 16, 0, 0);
}

// ---------------- fused prep (weight repack fp32->f16 B^T) + LN1 ----------------
__global__ __launch_bounds__(256) void prep_ln_kernel(
    const float* __restrict__ Wq, const float* __restrict__ Wk, const float* __restrict__ Wv,
    const float* __restrict__ bq, const float* __restrict__ bk, const float* __restrict__ bv,
    const float* __restrict__ Wp, const float* __restrict__ W1, const float* __restrict__ W2,
    f16* __restrict__ Wqkv_t, f16* __restrict__ Wp_t, f16* __restrict__ W1_t, f16* __restrict__ W2_t,
    float* __restrict__ bqkv,
    const float* __restrict__ x, const float* __restrict__ gamma, const float* __restrict__ beta,
    f16* __restrict__ hout)
{
  const int bid = blockIdx.x;
  const int tid = threadIdx.x;
  if (bid >= 217) {
    // ---- LN1: wave per row
    int row = (bid - 217) * 4 + (tid >> 6);
    int lane = tid & 63;
    const float* xr = x + (size_t)row * 384;
    float v[6]; float s = 0.f;
#pragma unroll
    for (int j = 0; j < 6; j++) { v[j] = xr[lane + 64*j]; s += v[j]; }
#pragma unroll
    for (int m = 1; m < 64; m <<= 1) s += __shfl_xor(s, m);
    float mu = s * (1.f/384.f);
    float var = 0.f;
#pragma unroll
    for (int j = 0; j < 6; j++) { float d = v[j]-mu; var += d*d; }
#pragma unroll
    for (int m = 1; m < 64; m <<= 1) var += __shfl_xor(var, m);
    float rs = rsqrtf(var * (1.f/384.f) + 1e-5f);
    f16* orow = hout + (size_t)row*384;
#pragma unroll
    for (int j = 0; j < 6; j++) {
      int col = lane + 64*j;
      orow[col] = (f16)((v[j]-mu)*rs*gamma[col] + beta[col]);
    }
    return;
  }
  if (bid == 216) {
    for (int i = tid; i < 1152; i += 256) {
      float v;
      if (i < 384)      v = bq[i];
      else if (i < 768) v = bk[i - 384];
      else              v = bv[i - 768];
      bqkv[i] = v;
    }
    return;
  }
  __shared__ __align__(16) float tile[64*68];
  const float* src; int srcStride; f16* dst;
  if (bid < 108) {
    int mat = bid / 36, rem = bid - mat*36;
    int h = rem / 6, kt = rem - h*6;
    const float* W = (mat == 0) ? Wq : (mat == 1) ? Wk : Wv;
    src = W + (size_t)(h*384 + kt*64)*64;
    srcStride = 64;
    dst = Wqkv_t + (size_t)(mat*384 + h*64)*384 + kt*64;
  } else {
    int b2 = bid - 108;
    int mat = b2 / 36, rem = b2 - mat*36;
    int kt = rem / 6, ct = rem - kt*6;
    const float* W = (mat == 0) ? Wp : (mat == 1) ? W1 : W2;
    src = W + (size_t)(kt*64)*384 + ct*64;
    srcStride = 384;
    f16* O = (mat == 0) ? Wp_t : (mat == 1) ? W1_t : W2_t;
    dst = O + (size_t)(ct*64)*384 + kt*64;
  }
#pragma unroll
  for (int i = 0; i < 4; i++) {
    int idx = i*256 + tid;
    int r = idx >> 4, c4 = idx & 15;
    float4 v = *(const float4*)(src + (size_t)r*srcStride + c4*4);
    *(float4*)(&tile[r*68 + c4*4]) = v;
  }
  __syncthreads();
#pragma unroll
  for (int i = 0; i < 4; i++) {
    int idx = i*256 + tid;
    int d = idx >> 4, k4 = idx & 15;
    half4v o;
#pragma unroll
    for (int j = 0; j < 4; j++) o[j] = (f16)tile[(k4*4 + j)*68 + d];
    *(half4v*)(dst + (size_t)d*384 + k4*4) = o;
  }
}

// ---------------- GEMM (QKV): C[M,1152] = A[M,384] @ Bt^T + bias, f16 out ----------------
// R1-proven 128x128 tile, BK=64.
__global__ __launch_bounds__(256) void gemm_qkv_kernel(
    const f16* __restrict__ A, const f16* __restrict__ Bt,
    const float* __restrict__ bias, f16* __restrict__ outp, int ldo)
{
  __shared__ __align__(16) f16 As[2][128*32];
  __shared__ __align__(16) f16 Bs[2][128*32];
  const int tid = threadIdx.x;
  const int lane = tid & 63, w = tid >> 6;
  const int wm = w >> 1, wn = w & 1;
  const int q = lane >> 4, c15 = lane & 15;
  const long row0 = (long)blockIdx.x * 128;
  const long col0 = (long)blockIdx.y * 128;
  floatx4 acc[4][4] = {};

  const int c0 = tid,        r0c = c0 >> 2, p0 = c0 & 3, g0 = p0 ^ ((r0c >> 1) & 3);
  const int c1 = 256 + tid,  r1c = c1 >> 2, p1 = c1 & 3, g1 = p1 ^ ((r1c >> 1) & 3);
  const f16* Arow0 = A  + (row0 + r0c)*384 + g0*8;
  const f16* Arow1 = A  + (row0 + r1c)*384 + g1*8;
  const f16* Brow0 = Bt + (col0 + r0c)*384 + g0*8;
  const f16* Brow1 = Bt + (col0 + r1c)*384 + g1*8;
  const int dof0 = (w*64)*8, dof1 = (256 + w*64)*8;

  for (int k0 = 0; k0 < 384; k0 += 64) {
#pragma unroll
    for (int hf = 0; hf < 2; hf++) {
      int kk = k0 + hf*32;
      g2lds16(Arow0 + kk, &As[hf][dof0]);
      g2lds16(Arow1 + kk, &As[hf][dof1]);
      g2lds16(Brow0 + kk, &Bs[hf][dof0]);
      g2lds16(Brow1 + kk, &Bs[hf][dof1]);
    }
    __syncthreads();
#pragma unroll
    for (int hf = 0; hf < 2; hf++) {
      half8 af[4], bf[4];
#pragma unroll
      for (int mi = 0; mi < 4; mi++) {
        int r = wm*64 + mi*16 + c15;
        int ph = q ^ ((r >> 1) & 3);
        af[mi] = *(const half8*)(&As[hf][r*32 + ph*8]);
      }
#pragma unroll
      for (int ni = 0; ni < 4; ni++) {
        int r = wn*64 + ni*16 + c15;
        int ph = q ^ ((r >> 1) & 3);
        bf[ni] = *(const half8*)(&Bs[hf][r*32 + ph*8]);
      }
#pragma unroll
      for (int mi = 0; mi < 4; mi++)
#pragma unroll
        for (int ni = 0; ni < 4; ni++)
          acc[mi][ni] = __builtin_amdgcn_mfma_f32_16x16x32_f16(af[mi], bf[ni], acc[mi][ni], 0, 0, 0);
    }
    __syncthreads();
  }

#pragma unroll
  for (int ni = 0; ni < 4; ni++) {
    long col = col0 + wn*64 + ni*16 + c15;
    float bv = bias[col];
#pragma unroll
    for (int mi = 0; mi < 4; mi++) {
      long rowb = row0 + wm*64 + mi*16 + q*4;
#pragma unroll
      for (int r = 0; r < 4; r++) {
        float vo = acc[mi][ni][r] + bv;
        outp[(rowb + r) * (long)ldo + col] = (f16)vo;
      }
    }
  }
}

// ---------------- fused causal attention (R6-proven) ----------------
__global__ __launch_bounds__(512, 2) void attn_kernel(const f16* __restrict__ qkv,
                                                      f16* __restrict__ attn_out)
{
  __shared__ __align__(16) char kvbuf[32768];
  __shared__ __align__(16) f16 Pbuf[8][16*64];
  f16* Ks = (f16*)kvbuf;
  unsigned int* vTw = (unsigned int*)kvbuf;
  f16* vT = (f16*)kvbuf;

  const int tid = threadIdx.x;
  const int bid = blockIdx.x;
  const int bh = bid >> 1, qt2 = bid & 1;
  const int b = bh / 6, h = bh - b*6;
  const f16* qp = qkv + (size_t)b*256*1152 + h*64;
  const f16* kp = qp + 384;
  const f16* vp = qp + 768;
  const int lane = tid & 63, w = tid >> 6;
  const int q = lane >> 4, c15 = lane & 15;

  {
    const int iters = (qt2 + 1) * 2;
    for (int i = 0; i < iters; i++) {
      int pc = i*512 + tid;
      int rc = pc >> 3, p = pc & 7;
      int c = p ^ (rc & 7);
      g2lds16(kp + (size_t)rc*1152 + c*8, (char*)kvbuf + (size_t)(i*512 + w*64)*16);
    }
  }

  const int nmax = qt2*8 + w;
  const int trow0 = qt2*128 + w*16;
  const f16* qrow = qp + (size_t)(trow0 + c15)*1152 + q*8;
  half8 aq0 = *(const half8*)(qrow);
  half8 aq1 = *(const half8*)(qrow + 32);

  __syncthreads();

  floatx4 sacc[16];
  __builtin_amdgcn_s_setprio(1);
#pragma unroll
  for (int ni = 0; ni < 16; ni++) {
    if (ni <= nmax) {
      int s = ni*16 + c15;
      const f16* kr = Ks + s*64;
      int p0 = q ^ (s & 7);
      half8 b0 = *(const half8*)(kr + p0*8);
      half8 b1 = *(const half8*)(kr + (p0 ^ 4)*8);
      floatx4 a = {0.f, 0.f, 0.f, 0.f};
      a = __builtin_amdgcn_mfma_f32_16x16x32_f16(aq0, b0, a, 0, 0, 0);
      a = __builtin_amdgcn_mfma_f32_16x16x32_f16(aq1, b1, a, 0, 0, 0);
      sacc[ni] = a;
    }
  }
  __builtin_amdgcn_s_setprio(0);
  __syncthreads();

  half8 va[2], vb[2];
#pragma unroll
  for (int i = 0; i < 2; i++) {
    if (i <= qt2) {
      int idx = i*512 + tid;
      int sp = idx >> 3, part = idx & 7;
      const f16* v0 = vp + (size_t)(2*sp)*1152 + part*8;
      va[i] = *(const half8*)(v0);
      vb[i] = *(const half8*)(v0 + 1152);
    }
  }

  const float scale = 0.051031036307982884f;
  float mx[4] = {-1e30f, -1e30f, -1e30f, -1e30f};
#pragma unroll
  for (int ni = 0; ni < 16; ni++) {
    if (ni < nmax) {
#pragma unroll
      for (int r = 0; r < 4; r++) { float v = sacc[ni][r]*scale; sacc[ni][r] = v; mx[r] = fmaxf(mx[r], v); }
    } else if (ni == nmax) {
#pragma unroll
      for (int r = 0; r < 4; r++) {
        float v = sacc[ni][r]*scale;
        v = (c15 <= q*4 + r) ? v : -1e30f;
        sacc[ni][r] = v; mx[r] = fmaxf(mx[r], v);
      }
    }
  }
#pragma unroll
  for (int r = 0; r < 4; r++) {
    mx[r] = fmaxf(mx[r], __shfl_xor(mx[r], 1));
    mx[r] = fmaxf(mx[r], __shfl_xor(mx[r], 2));
    mx[r] = fmaxf(mx[r], __shfl_xor(mx[r], 4));
    mx[r] = fmaxf(mx[r], __shfl_xor(mx[r], 8));
  }
  float l[4] = {0.f, 0.f, 0.f, 0.f};
#pragma unroll
  for (int ni = 0; ni < 16; ni++) {
    if (ni <= nmax) {
#pragma unroll
      for (int r = 0; r < 4; r++) { float p = __expf(sacc[ni][r] - mx[r]); sacc[ni][r] = p; l[r] += p; }
    }
  }
#pragma unroll
  for (int r = 0; r < 4; r++) {
    l[r] += __shfl_xor(l[r], 1);
    l[r] += __shfl_xor(l[r], 2);
    l[r] += __shfl_xor(l[r], 4);
    l[r] += __shfl_xor(l[r], 8);
  }

#pragma unroll
  for (int i = 0; i < 2; i++) {
    if (i <= qt2) {
      int idx = i*512 + tid;
      int sp = idx >> 3, part = idx & 7;
      int csp = sp >> 2, spw = sp & 3;
#pragma unroll
      for (int j = 0; j < 8; j++) {
        int d = part*8 + j;
        int swz = (d & 15) ^ (d >> 3);
        int p = csp ^ swz;
        union { struct { f16 lo, hi; } s; unsigned int u; } pk;
        pk.s.lo = va[i][j]; pk.s.hi = vb[i][j];
        vTw[d*128 + p*4 + spw] = pk.u;
      }
    }
  }
  __syncthreads();

  f16* Pw = &Pbuf[w][0];
  floatx4 oacc[4] = {};
  const int kend_w = (nmax + 1) * 16;
#pragma unroll
  for (int ch = 0; ch < 4; ch++) {
    if (ch*64 < kend_w) {
#pragma unroll
      for (int nl = 0; nl < 4; nl++) {
        int ni = ch*4 + nl;
        if (ni <= nmax) {
#pragma unroll
          for (int r = 0; r < 4; r++) {
            int row = q*4 + r;
            int colp = nl*16 + c15;
            int php = (colp >> 3) ^ (row & 7);
            Pw[row*64 + php*8 + (colp & 7)] = (f16)sacc[ni][r];
          }
        } else if (ni == nmax + 1) {
#pragma unroll
          for (int r = 0; r < 4; r++) {
            int row = q*4 + r;
            int colp = nl*16 + c15;
            int php = (colp >> 3) ^ (row & 7);
            Pw[row*64 + php*8 + (colp & 7)] = (f16)0.f;
          }
        }
      }
      __builtin_amdgcn_s_setprio(1);
#pragma unroll
      for (int kc = 0; kc < 2; kc++) {
        if (ch*64 + kc*32 < kend_w) {
          int pc = (kc*4 + q) ^ (c15 & 7);
          half8 ap = *(const half8*)(Pw + c15*64 + pc*8);
          int sc = ch*8 + kc*4 + q;
#pragma unroll
          for (int nt = 0; nt < 4; nt++) {
            int d = nt*16 + c15;
            int swz = (d & 15) ^ (d >> 3);
            half8 bv = *(const half8*)(vT + d*256 + ((sc ^ swz))*8);
            oacc[nt] = __builtin_amdgcn_mfma_f32_16x16x32_f16(ap, bv, oacc[nt], 0, 0, 0);
          }
        }
      }
      __builtin_amdgcn_s_setprio(0);
    }
  }

  float rl[4];
#pragma unroll
  for (int r = 0; r < 4; r++) rl[r] = 1.0f / l[r];
#pragma unroll
  for (int nt = 0; nt < 4; nt++) {
#pragma unroll
    for (int r = 0; r < 4; r++) {
      int t = trow0 + q*4 + r;
      int d = nt*16 + c15;
      attn_out[(size_t)(b*256 + t)*384 + h*64 + d] = (f16)(oacc[nt][r] * rl[r]);
    }
  }
}

// ---------------- fused tail: proj + residual + LN2 + FF1 + FF2 ----------------
// R8: BK=64 (6 steps/phase, 18 total vs R7's 36) + single 48KB rowbuf that is
// A-full during phase a, then ALIASED as h2 (phase b A-operand) then as mid
// (phase c A-operand). Writes are row-partitioned per-wave identically to
// reads; LN barriers (phase a) / one added barrier (phase b) order the
// overwrites. x residual prefetched to registers (latency hidden under GEMM).
// W1/W2 Bs[0] staging overlapped with LN / epilogue barriers.
// LDS: 48K rowbuf + 96K Bs dbuf + 2.5K ln = ~146.5KB (1 block/CU; VGPR-free
// at 2 waves/SIMD so __launch_bounds__(512,2)).
__global__ __launch_bounds__(512, 2) void tail_kernel(
    const f16* __restrict__ A, const f16* __restrict__ WpT,
    const f16* __restrict__ W1T, const f16* __restrict__ W2T,
    const float* __restrict__ bp, const float* __restrict__ b1, const float* __restrict__ b2,
    const float* __restrict__ x, const float* __restrict__ g2, const float* __restrict__ be2,
    float* __restrict__ out)
{
  __shared__ __align__(16) f16 rowbuf[12*64*32];   // 49152B: A-full / h2 / mid
  __shared__ __align__(16) f16 Bs[2][384*64];      // 98304B
  __shared__ float lnred[2][64][4];
  __shared__ float lnmv[2][64];

  const int tid = threadIdx.x;
  const int lane = tid & 63, w = tid >> 6;
  const int wm = w >> 2, wn = w & 3;
  const int q = lane >> 4, c15 = lane & 15;
  const long row0 = (long)blockIdx.x * 64;

  // ---- staging offsets (16B chunks; XOR-swizzled k-groups) ----
  // A-full: 3072 chunks, layout [kc 0..11][row*32 + slot*8]
  long offA[6];
#pragma unroll
  for (int i = 0; i < 6; i++) {
    int cb = i*512 + tid;
    int kc = cb >> 8, c2 = cb & 255;
    int rA = c2 >> 2, pA = c2 & 3, gA = pA ^ ((rA >> 1) & 3);
    offA[i] = (row0 + rA)*384 + kc*32 + gA*8;
  }
  // B step (BK=64): 3072 chunks, layout [row][half*32 + slot*8]
  long offB[6];
#pragma unroll
  for (int i = 0; i < 6; i++) {
    int cb = i*512 + tid;
    int rc = cb >> 3, r3 = cb & 7;
    int hh = r3 >> 2, p = r3 & 3, g = p ^ ((rc >> 1) & 3);
    offB[i] = (long)rc*384 + hh*32 + g*8;
  }

  floatx4 acc[2][6] = {};

#define T_STAGE_AFULL() do { \
    _Pragma("unroll") \
    for (int i = 0; i < 6; i++) \
      g2lds16(A + offA[i], (char*)rowbuf + (size_t)(i*512 + w*64)*16); \
  } while (0)

#define T_STAGE_B(buf, kk, BT) do { \
    _Pragma("unroll") \
    for (int i = 0; i < 6; i++) \
      g2lds16(BT + offB[i] + (kk), (char*)(&Bs[buf][0]) + (size_t)(i*512 + w*64)*16); \
  } while (0)

#define T_COMP64(a0, buf) do { \
    half8 af[2][2], bf[2][6]; \
    _Pragma("unroll") \
    for (int ks = 0; ks < 2; ks++) { \
      _Pragma("unroll") \
      for (int mi = 0; mi < 2; mi++) { \
        int r = wm*32 + mi*16 + c15; \
        int ph = q ^ ((r >> 1) & 3); \
        af[ks][mi] = *(const half8*)(&rowbuf[((a0) + ks)*2048 + r*32 + ph*8]); \
      } \
      _Pragma("unroll") \
      for (int ni = 0; ni < 6; ni++) { \
        int rb = wn*96 + ni*16 + c15; \
        int phb = q ^ ((rb >> 1) & 3); \
        bf[ks][ni] = *(const half8*)(&Bs[buf][rb*64 + ks*32 + phb*8]); \
      } \
    } \
    _Pragma("unroll") \
    for (int ks = 0; ks < 2; ks++) \
      _Pragma("unroll") \
      for (int mi = 0; mi < 2; mi++) \
        _Pragma("unroll") \
        for (int ni = 0; ni < 6; ni++) \
          acc[mi][ni] = __builtin_amdgcn_mfma_f32_16x16x32_f16(af[ks][mi], bf[ks][ni], acc[mi][ni], 0, 0, 0); \
  } while (0)

  // ================= phase a: x2 = x + A@Wp + bp ; h2 = LN2(x2) =================
  T_STAGE_AFULL();
  T_STAGE_B(0, 0, WpT);
  // prefetch x residual into registers (consumed at epilogue a; hides under GEMM)
  float xv[2][6][4];
#pragma unroll
  for (int mi = 0; mi < 2; mi++)
#pragma unroll
    for (int rr = 0; rr < 4; rr++) {
      long row = row0 + wm*32 + mi*16 + q*4 + rr;
#pragma unroll
      for (int ni = 0; ni < 6; ni++)
        xv[mi][ni][rr] = x[row*384 + wn*96 + ni*16 + c15];
    }
  __syncthreads();
#pragma unroll
  for (int t = 0; t < 5; ++t) {
    T_STAGE_B((t + 1) & 1, (t + 1) * 64, WpT);
    T_COMP64(2*t, t & 1);
    __syncthreads();
  }
  T_COMP64(10, 1);
  T_STAGE_B(0, 0, W1T);   // overlap W1 first tile with LN barriers below

  float vals[2][6][4];
  {
    float colb[6], cg[6], cb2[6];
#pragma unroll
    for (int ni = 0; ni < 6; ni++) {
      int col = wn*96 + ni*16 + c15;
      colb[ni] = bp[col]; cg[ni] = g2[col]; cb2[ni] = be2[col];
    }
#pragma unroll
    for (int mi = 0; mi < 2; mi++)
#pragma unroll
      for (int rr = 0; rr < 4; rr++)
#pragma unroll
        for (int ni = 0; ni < 6; ni++)
          vals[mi][ni][rr] = acc[mi][ni][rr] + colb[ni] + xv[mi][ni][rr];
    // per-row partial sums over this wave's 96 cols
#pragma unroll
    for (int mi = 0; mi < 2; mi++) {
#pragma unroll
      for (int rr = 0; rr < 4; rr++) {
        float s = 0.f, s2 = 0.f;
#pragma unroll
        for (int ni = 0; ni < 6; ni++) { float v = vals[mi][ni][rr]; s += v; s2 += v*v; }
        s  += __shfl_xor(s, 1);  s  += __shfl_xor(s, 2);  s  += __shfl_xor(s, 4);  s  += __shfl_xor(s, 8);
        s2 += __shfl_xor(s2, 1); s2 += __shfl_xor(s2, 2); s2 += __shfl_xor(s2, 4); s2 += __shfl_xor(s2, 8);
        if (c15 == 0) {
          int lr = wm*32 + mi*16 + q*4 + rr;
          lnred[0][lr][wn] = s;
          lnred[1][lr][wn] = s2;
        }
      }
    }
    __syncthreads();      // also: all A-reads complete before rowbuf overwrite
    if (tid < 64) {
      float s = 0.f, s2 = 0.f;
#pragma unroll
      for (int j = 0; j < 4; j++) { s += lnred[0][tid][j]; s2 += lnred[1][tid][j]; }
      float mu = s * (1.f/384.f);
      float var = s2 * (1.f/384.f) - mu*mu;
      lnmv[0][tid] = mu;
      lnmv[1][tid] = rsqrtf(var + 1e-5f);
    }
    __syncthreads();
    // normalize -> h2 into rowbuf (staged-A swizzled layout)
#pragma unroll
    for (int mi = 0; mi < 2; mi++) {
#pragma unroll
      for (int rr = 0; rr < 4; rr++) {
        int lr = wm*32 + mi*16 + q*4 + rr;
        float mu = lnmv[0][lr], rs = lnmv[1][lr];
        int s_ = (lr >> 1) & 3;
#pragma unroll
        for (int ni = 0; ni < 6; ni++) {
          int cc = wn*96 + ni*16 + c15;
          float hv = (vals[mi][ni][rr] - mu)*rs*cg[ni] + cb2[ni];
          int chunk = cc >> 5, kk2 = cc & 31;
          int pos = ((kk2 >> 3) ^ s_)*8 + (kk2 & 7);
          rowbuf[chunk*2048 + lr*32 + pos] = (f16)hv;
        }
      }
    }
  }
  __syncthreads();   // publish h2 + drain W1 Bs[0]

  // ================= phase b: mid = relu(h2 @ W1 + b1) =================
#pragma unroll
  for (int mi = 0; mi < 2; mi++)
#pragma unroll
    for (int ni = 0; ni < 6; ni++)
      acc[mi][ni] = floatx4{0.f, 0.f, 0.f, 0.f};
#pragma unroll
  for (int t = 0; t < 5; ++t) {
    T_STAGE_B((t + 1) & 1, (t + 1) * 64, W1T);
    T_COMP64(2*t, t & 1);
    __syncthreads();
  }
  T_COMP64(10, 1);
  T_STAGE_B(0, 0, W2T);   // overlap W2 first tile
  __syncthreads();        // all h2 reads complete before rowbuf overwrite

  {
    float colb[6];
#pragma unroll
    for (int ni = 0; ni < 6; ni++) colb[ni] = b1[wn*96 + ni*16 + c15];
#pragma unroll
    for (int mi = 0; mi < 2; mi++) {
#pragma unroll
      for (int rr = 0; rr < 4; rr++) {
        int lr = wm*32 + mi*16 + q*4 + rr;
        int s_ = (lr >> 1) & 3;
#pragma unroll
        for (int ni = 0; ni < 6; ni++) {
          int cc = wn*96 + ni*16 + c15;
          float v = acc[mi][ni][rr] + colb[ni];
          v = v > 0.f ? v : 0.f;
          int chunk = cc >> 5, kk2 = cc & 31;
          int pos = ((kk2 >> 3) ^ s_)*8 + (kk2 & 7);
          rowbuf[chunk*2048 + lr*32 + pos] = (f16)v;
        }
      }
    }
  }
  __syncthreads();   // publish mid + drain W2 Bs[0]

  // ================= phase c: out = x2 + mid @ W2 + b2 =================
#pragma unroll
  for (int mi = 0; mi < 2; mi++)
#pragma unroll
    for (int ni = 0; ni < 6; ni++)
      acc[mi][ni] = floatx4{0.f, 0.f, 0.f, 0.f};
#pragma unroll
  for (int t = 0; t < 5; ++t) {
    T_STAGE_B((t + 1) & 1, (t + 1) * 64, W2T);
    T_COMP64(2*t, t & 1);
    __syncthreads();
  }
  T_COMP64(10, 1);

  {
    float colb[6];
#pragma unroll
    for (int ni = 0; ni < 6; ni++) colb[ni] = b2[wn*96 + ni*16 + c15];
#pragma unroll
    for (int mi = 0; mi < 2; mi++) {
#pragma unroll
      for (int rr = 0; rr < 4; rr++) {
        long row = row0 + wm*32 + mi*16 + q*4 + rr;
#pragma unroll
        for (int ni = 0; ni < 6; ni++) {
          int col = wn*96 + ni*16 + c15;
          out[row*384 + col] = acc[mi][ni][rr] + colb[ni] + vals[mi][ni][rr];
        }
      }
    }
  }

#undef T_STAGE_AFULL
#undef T_STAGE_B
#undef T_COMP64
}

extern "C" void kernel_launch(void* const* d_in, const int* in_sizes, int n_in,
                              void* d_out, int out_size, void* d_ws, size_t ws_size,
                              hipStream_t stream) {
  const float* x   = (const float*)d_in[0];
  const float* Wq  = (const float*)d_in[1];
  const float* bq  = (const float*)d_in[2];
  const float* Wk  = (const float*)d_in[3];
  const float* bk  = (const float*)d_in[4];
  const float* Wv  = (const float*)d_in[5];
  const float* bv  = (const float*)d_in[6];
  const float* Wp  = (const float*)d_in[7];
  const float* bp  = (const float*)d_in[8];
  const float* W1  = (const float*)d_in[9];
  const float* b1  = (const float*)d_in[10];
  const float* W2  = (const float*)d_in[11];
  const float* b2  = (const float*)d_in[12];
  const float* g1  = (const float*)d_in[13];
  const float* be1 = (const float*)d_in[14];
  const float* g2  = (const float*)d_in[15];
  const float* be2 = (const float*)d_in[16];

  char* ws = (char*)d_ws;
  size_t off = 0;
  auto alloc = [&](size_t bytes) -> void* {
    void* p = ws + off;
    off += (bytes + 255) & ~(size_t)255;
    return p;
  };
  f16*   Wqkv_t = (f16*)  alloc(1152*384*sizeof(f16));
  f16*   Wp_t   = (f16*)  alloc(384*384*sizeof(f16));
  f16*   W1_t   = (f16*)  alloc(384*384*sizeof(f16));
  f16*   W2_t   = (f16*)  alloc(384*384*sizeof(f16));
  float* bqkv   = (float*)alloc(1152*sizeof(float));
  f16*   h      = (f16*)  alloc((size_t)NROWS*384*sizeof(f16));
  f16*   qkv    = (f16*)  alloc((size_t)NROWS*1152*sizeof(f16));
  f16*   attnb  = (f16*)  alloc((size_t)NROWS*384*sizeof(f16));

  // 1. fused: weight repack + LN1
  prep_ln_kernel<<<217 + NROWS/4, 256, 0, stream>>>(Wq, Wk, Wv, bq, bk, bv, Wp, W1, W2,
                                                    Wqkv_t, Wp_t, W1_t, W2_t, bqkv,
                                                    x, g1, be1, h);
  // 2. QKV: qkv[16384,1152] = h @ Wqkv + bqkv (f16 out)
  gemm_qkv_kernel<<<dim3(128, 9), 256, 0, stream>>>(h, Wqkv_t, bqkv, qkv, 1152);
  // 3. attention: 768 blocks x 512 threads (2 q-tiles per block)
  attn_kernel<<<B_*H_*2, 512, 0, stream>>>(qkv, attnb);
  // 4. fused tail: proj + residual + LN2 + FF1 + FF2 (BK=64, aliased rowbuf)
  tail_kernel<<<NROWS/64, 512, 0, stream>>>(attnb, Wp_t, W1_t, W2_t, bp, b1, b2,
                                            x, g2, be2, (float*)d_out);
}

// Round 9
// 181.751 us; speedup vs baseline: 1.2843x; 1.0128x over previous
//
#include <hip/hip_runtime.h>

typedef _Float16 f16;
typedef _Float16 half8 __attribute__((ext_vector_type(8)));
typedef _Float16 half4v __attribute__((ext_vector_type(4)));
typedef float floatx4 __attribute__((ext_vector_type(4)));

#define B_ 64
#define T_ 256
#define C_ 384
#define H_ 6
#define D_ 64
#define NROWS (B_*T_)

typedef __attribute__((address_space(3))) void lds_void_t;
typedef const __attribute__((address_space(1))) void gvoid_t;

__device__ __forceinline__ void g2lds16(const void* g, void* l) {
  __builtin_amdgcn_global_load_lds((gvoid_t*)g, (lds_void_t*)l, 16, 0, 0);
}

// ---------------- fused prep (weight repack fp32->f16) + LN1 ----------------
// blocks 0..107: Wq/Wk/Wv head-tiles -> B^T row-major (for LDS-staged QKV GEMM);
// blocks 108..215: Wp/W1/W2 64x64 tiles -> FRAGMENT-MAJOR layout (R9): each
// (16-col x 32-k) MFMA B-fragment tile = contiguous 1KB block, lane-ordered so
// a wave's fragment load is one coalesced global_load_dwordx4 from L2.
//   element (col, k) -> Wrep[((k>>5)*24 + (col>>4))*512 + (((k>>3)&3)*16 + (col&15))*8 + (k&7)]
// blocks 216: biases; 217..4312: LN1 rows (4 rows/block).
__global__ __launch_bounds__(256) void prep_ln_kernel(
    const float* __restrict__ Wq, const float* __restrict__ Wk, const float* __restrict__ Wv,
    const float* __restrict__ bq, const float* __restrict__ bk, const float* __restrict__ bv,
    const float* __restrict__ Wp, const float* __restrict__ W1, const float* __restrict__ W2,
    f16* __restrict__ Wqkv_t, f16* __restrict__ Wp_t, f16* __restrict__ W1_t, f16* __restrict__ W2_t,
    float* __restrict__ bqkv,
    const float* __restrict__ x, const float* __restrict__ gamma, const float* __restrict__ beta,
    f16* __restrict__ hout)
{
  const int bid = blockIdx.x;
  const int tid = threadIdx.x;
  if (bid >= 217) {
    // ---- LN1: wave per row
    int row = (bid - 217) * 4 + (tid >> 6);
    int lane = tid & 63;
    const float* xr = x + (size_t)row * 384;
    float v[6]; float s = 0.f;
#pragma unroll
    for (int j = 0; j < 6; j++) { v[j] = xr[lane + 64*j]; s += v[j]; }
#pragma unroll
    for (int m = 1; m < 64; m <<= 1) s += __shfl_xor(s, m);
    float mu = s * (1.f/384.f);
    float var = 0.f;
#pragma unroll
    for (int j = 0; j < 6; j++) { float d = v[j]-mu; var += d*d; }
#pragma unroll
    for (int m = 1; m < 64; m <<= 1) var += __shfl_xor(var, m);
    float rs = rsqrtf(var * (1.f/384.f) + 1e-5f);
    f16* orow = hout + (size_t)row*384;
#pragma unroll
    for (int j = 0; j < 6; j++) {
      int col = lane + 64*j;
      orow[col] = (f16)((v[j]-mu)*rs*gamma[col] + beta[col]);
    }
    return;
  }
  if (bid == 216) {
    for (int i = tid; i < 1152; i += 256) {
      float v;
      if (i < 384)      v = bq[i];
      else if (i < 768) v = bk[i - 384];
      else              v = bv[i - 768];
      bqkv[i] = v;
    }
    return;
  }
  __shared__ __align__(16) float tile[64*68];
  const float* src; int srcStride; f16* dst = nullptr;
  f16* O = nullptr; int kt_ = 0, ct_ = 0; bool frag = false;
  if (bid < 108) {
    int mat = bid / 36, rem = bid - mat*36;
    int h = rem / 6, kt = rem - h*6;
    const float* W = (mat == 0) ? Wq : (mat == 1) ? Wk : Wv;
    src = W + (size_t)(h*384 + kt*64)*64;
    srcStride = 64;
    dst = Wqkv_t + (size_t)(mat*384 + h*64)*384 + kt*64;
  } else {
    int b2 = bid - 108;
    int mat = b2 / 36, rem = b2 - mat*36;
    kt_ = rem / 6; ct_ = rem - kt_*6;
    const float* W = (mat == 0) ? Wp : (mat == 1) ? W1 : W2;
    src = W + (size_t)(kt_*64)*384 + ct_*64;
    srcStride = 384;
    O = (mat == 0) ? Wp_t : (mat == 1) ? W1_t : W2_t;
    frag = true;
  }
#pragma unroll
  for (int i = 0; i < 4; i++) {
    int idx = i*256 + tid;
    int r = idx >> 4, c4 = idx & 15;
    float4 v = *(const float4*)(src + (size_t)r*srcStride + c4*4);
    *(float4*)(&tile[r*68 + c4*4]) = v;
  }
  __syncthreads();
#pragma unroll
  for (int i = 0; i < 4; i++) {
    int idx = i*256 + tid;
    int d = idx >> 4, k4 = idx & 15;     // d: col within tile, k4: k-group of 4
    half4v o;
#pragma unroll
    for (int j = 0; j < 4; j++) o[j] = (f16)tile[(k4*4 + j)*68 + d];
    if (!frag) {
      *(half4v*)(dst + (size_t)d*384 + k4*4) = o;
    } else {
      // k = kt_*64 + k4*4 + j ; col = ct_*64 + d
      int ks    = kt_*2 + (k4 >> 3);
      int ctile = ct_*4 + (d >> 4);
      int slotq = (k4 >> 1) & 3;
      size_t off = (size_t)(ks*24 + ctile)*512 + (size_t)(slotq*16 + (d & 15))*8 + (k4 & 1)*4;
      *(half4v*)(O + off) = o;
    }
  }
}

// ---------------- GEMM (QKV): C[M,1152] = A[M,384] @ Bt^T + bias, f16 out ----------------
// R1-proven 128x128 tile, BK=64.
__global__ __launch_bounds__(256) void gemm_qkv_kernel(
    const f16* __restrict__ A, const f16* __restrict__ Bt,
    const float* __restrict__ bias, f16* __restrict__ outp, int ldo)
{
  __shared__ __align__(16) f16 As[2][128*32];
  __shared__ __align__(16) f16 Bs[2][128*32];
  const int tid = threadIdx.x;
  const int lane = tid & 63, w = tid >> 6;
  const int wm = w >> 1, wn = w & 1;
  const int q = lane >> 4, c15 = lane & 15;
  const long row0 = (long)blockIdx.x * 128;
  const long col0 = (long)blockIdx.y * 128;
  floatx4 acc[4][4] = {};

  const int c0 = tid,        r0c = c0 >> 2, p0 = c0 & 3, g0 = p0 ^ ((r0c >> 1) & 3);
  const int c1 = 256 + tid,  r1c = c1 >> 2, p1 = c1 & 3, g1 = p1 ^ ((r1c >> 1) & 3);
  const f16* Arow0 = A  + (row0 + r0c)*384 + g0*8;
  const f16* Arow1 = A  + (row0 + r1c)*384 + g1*8;
  const f16* Brow0 = Bt + (col0 + r0c)*384 + g0*8;
  const f16* Brow1 = Bt + (col0 + r1c)*384 + g1*8;
  const int dof0 = (w*64)*8, dof1 = (256 + w*64)*8;

  for (int k0 = 0; k0 < 384; k0 += 64) {
#pragma unroll
    for (int hf = 0; hf < 2; hf++) {
      int kk = k0 + hf*32;
      g2lds16(Arow0 + kk, &As[hf][dof0]);
      g2lds16(Arow1 + kk, &As[hf][dof1]);
      g2lds16(Brow0 + kk, &Bs[hf][dof0]);
      g2lds16(Brow1 + kk, &Bs[hf][dof1]);
    }
    __syncthreads();
#pragma unroll
    for (int hf = 0; hf < 2; hf++) {
      half8 af[4], bf[4];
#pragma unroll
      for (int mi = 0; mi < 4; mi++) {
        int r = wm*64 + mi*16 + c15;
        int ph = q ^ ((r >> 1) & 3);
        af[mi] = *(const half8*)(&As[hf][r*32 + ph*8]);
      }
#pragma unroll
      for (int ni = 0; ni < 4; ni++) {
        int r = wn*64 + ni*16 + c15;
        int ph = q ^ ((r >> 1) & 3);
        bf[ni] = *(const half8*)(&Bs[hf][r*32 + ph*8]);
      }
#pragma unroll
      for (int mi = 0; mi < 4; mi++)
#pragma unroll
        for (int ni = 0; ni < 4; ni++)
          acc[mi][ni] = __builtin_amdgcn_mfma_f32_16x16x32_f16(af[mi], bf[ni], acc[mi][ni], 0, 0, 0);
    }
    __syncthreads();
  }

#pragma unroll
  for (int ni = 0; ni < 4; ni++) {
    long col = col0 + wn*64 + ni*16 + c15;
    float bv = bias[col];
#pragma unroll
    for (int mi = 0; mi < 4; mi++) {
      long rowb = row0 + wm*64 + mi*16 + q*4;
#pragma unroll
      for (int r = 0; r < 4; r++) {
        float vo = acc[mi][ni][r] + bv;
        outp[(rowb + r) * (long)ldo + col] = (f16)vo;
      }
    }
  }
}

// ---------------- fused causal attention (R6-proven) ----------------
__global__ __launch_bounds__(512, 2) void attn_kernel(const f16* __restrict__ qkv,
                                                      f16* __restrict__ attn_out)
{
  __shared__ __align__(16) char kvbuf[32768];
  __shared__ __align__(16) f16 Pbuf[8][16*64];
  f16* Ks = (f16*)kvbuf;
  unsigned int* vTw = (unsigned int*)kvbuf;
  f16* vT = (f16*)kvbuf;

  const int tid = threadIdx.x;
  const int bid = blockIdx.x;
  const int bh = bid >> 1, qt2 = bid & 1;
  const int b = bh / 6, h = bh - b*6;
  const f16* qp = qkv + (size_t)b*256*1152 + h*64;
  const f16* kp = qp + 384;
  const f16* vp = qp + 768;
  const int lane = tid & 63, w = tid >> 6;
  const int q = lane >> 4, c15 = lane & 15;

  {
    const int iters = (qt2 + 1) * 2;
    for (int i = 0; i < iters; i++) {
      int pc = i*512 + tid;
      int rc = pc >> 3, p = pc & 7;
      int c = p ^ (rc & 7);
      g2lds16(kp + (size_t)rc*1152 + c*8, (char*)kvbuf + (size_t)(i*512 + w*64)*16);
    }
  }

  const int nmax = qt2*8 + w;
  const int trow0 = qt2*128 + w*16;
  const f16* qrow = qp + (size_t)(trow0 + c15)*1152 + q*8;
  half8 aq0 = *(const half8*)(qrow);
  half8 aq1 = *(const half8*)(qrow + 32);

  __syncthreads();

  floatx4 sacc[16];
  __builtin_amdgcn_s_setprio(1);
#pragma unroll
  for (int ni = 0; ni < 16; ni++) {
    if (ni <= nmax) {
      int s = ni*16 + c15;
      const f16* kr = Ks + s*64;
      int p0 = q ^ (s & 7);
      half8 b0 = *(const half8*)(kr + p0*8);
      half8 b1 = *(const half8*)(kr + (p0 ^ 4)*8);
      floatx4 a = {0.f, 0.f, 0.f, 0.f};
      a = __builtin_amdgcn_mfma_f32_16x16x32_f16(aq0, b0, a, 0, 0, 0);
      a = __builtin_amdgcn_mfma_f32_16x16x32_f16(aq1, b1, a, 0, 0, 0);
      sacc[ni] = a;
    }
  }
  __builtin_amdgcn_s_setprio(0);
  __syncthreads();

  half8 va[2], vb[2];
#pragma unroll
  for (int i = 0; i < 2; i++) {
    if (i <= qt2) {
      int idx = i*512 + tid;
      int sp = idx >> 3, part = idx & 7;
      const f16* v0 = vp + (size_t)(2*sp)*1152 + part*8;
      va[i] = *(const half8*)(v0);
      vb[i] = *(const half8*)(v0 + 1152);
    }
  }

  const float scale = 0.051031036307982884f;
  float mx[4] = {-1e30f, -1e30f, -1e30f, -1e30f};
#pragma unroll
  for (int ni = 0; ni < 16; ni++) {
    if (ni < nmax) {
#pragma unroll
      for (int r = 0; r < 4; r++) { float v = sacc[ni][r]*scale; sacc[ni][r] = v; mx[r] = fmaxf(mx[r], v); }
    } else if (ni == nmax) {
#pragma unroll
      for (int r = 0; r < 4; r++) {
        float v = sacc[ni][r]*scale;
        v = (c15 <= q*4 + r) ? v : -1e30f;
        sacc[ni][r] = v; mx[r] = fmaxf(mx[r], v);
      }
    }
  }
#pragma unroll
  for (int r = 0; r < 4; r++) {
    mx[r] = fmaxf(mx[r], __shfl_xor(mx[r], 1));
    mx[r] = fmaxf(mx[r], __shfl_xor(mx[r], 2));
    mx[r] = fmaxf(mx[r], __shfl_xor(mx[r], 4));
    mx[r] = fmaxf(mx[r], __shfl_xor(mx[r], 8));
  }
  float l[4] = {0.f, 0.f, 0.f, 0.f};
#pragma unroll
  for (int ni = 0; ni < 16; ni++) {
    if (ni <= nmax) {
#pragma unroll
      for (int r = 0; r < 4; r++) { float p = __expf(sacc[ni][r] - mx[r]); sacc[ni][r] = p; l[r] += p; }
    }
  }
#pragma unroll
  for (int r = 0; r < 4; r++) {
    l[r] += __shfl_xor(l[r], 1);
    l[r] += __shfl_xor(l[r], 2);
    l[r] += __shfl_xor(l[r], 4);
    l[r] += __shfl_xor(l[r], 8);
  }

#pragma unroll
  for (int i = 0; i < 2; i++) {
    if (i <= qt2) {
      int idx = i*512 + tid;
      int sp = idx >> 3, part = idx & 7;
      int csp = sp >> 2, spw = sp & 3;
#pragma unroll
      for (int j = 0; j < 8; j++) {
        int d = part*8 + j;
        int swz = (d & 15) ^ (d >> 3);
        int p = csp ^ swz;
        union { struct { f16 lo, hi; } s; unsigned int u; } pk;
        pk.s.lo = va[i][j]; pk.s.hi = vb[i][j];
        vTw[d*128 + p*4 + spw] = pk.u;
      }
    }
  }
  __syncthreads();

  f16* Pw = &Pbuf[w][0];
  floatx4 oacc[4] = {};
  const int kend_w = (nmax + 1) * 16;
#pragma unroll
  for (int ch = 0; ch < 4; ch++) {
    if (ch*64 < kend_w) {
#pragma unroll
      for (int nl = 0; nl < 4; nl++) {
        int ni = ch*4 + nl;
        if (ni <= nmax) {
#pragma unroll
          for (int r = 0; r < 4; r++) {
            int row = q*4 + r;
            int colp = nl*16 + c15;
            int php = (colp >> 3) ^ (row & 7);
            Pw[row*64 + php*8 + (colp & 7)] = (f16)sacc[ni][r];
          }
        } else if (ni == nmax + 1) {
#pragma unroll
          for (int r = 0; r < 4; r++) {
            int row = q*4 + r;
            int colp = nl*16 + c15;
            int php = (colp >> 3) ^ (row & 7);
            Pw[row*64 + php*8 + (colp & 7)] = (f16)0.f;
          }
        }
      }
      __builtin_amdgcn_s_setprio(1);
#pragma unroll
      for (int kc = 0; kc < 2; kc++) {
        if (ch*64 + kc*32 < kend_w) {
          int pc = (kc*4 + q) ^ (c15 & 7);
          half8 ap = *(const half8*)(Pw + c15*64 + pc*8);
          int sc = ch*8 + kc*4 + q;
#pragma unroll
          for (int nt = 0; nt < 4; nt++) {
            int d = nt*16 + c15;
            int swz = (d & 15) ^ (d >> 3);
            half8 bv = *(const half8*)(vT + d*256 + ((sc ^ swz))*8);
            oacc[nt] = __builtin_amdgcn_mfma_f32_16x16x32_f16(ap, bv, oacc[nt], 0, 0, 0);
          }
        }
      }
      __builtin_amdgcn_s_setprio(0);
    }
  }

  float rl[4];
#pragma unroll
  for (int r = 0; r < 4; r++) rl[r] = 1.0f / l[r];
#pragma unroll
  for (int nt = 0; nt < 4; nt++) {
#pragma unroll
    for (int r = 0; r < 4; r++) {
      int t = trow0 + q*4 + r;
      int d = nt*16 + c15;
      attn_out[(size_t)(b*256 + t)*384 + h*64 + d] = (f16)(oacc[nt][r] * rl[r]);
    }
  }
}

// ---------------- fused tail: proj + residual + LN2 + FF1 + FF2 ----------------
// R9: ZERO barriers in the K-loops. B operands (Wp/W1/W2) are read directly
// from L2 in fragment-major layout (see prep_ln) via coalesced
// global_load_dwordx4 -- no Bs LDS, no staging, no block-wide vmcnt drains;
// each wave waits only on its own loads and the compiler pipelines the fully
// unrolled 12-step loop. A stays in rowbuf (48KB LDS), aliased A -> h2 -> mid
// across phases (R8-proven swizzle pairs). Barriers: 18 -> 6.
// LDS ~50.5KB. __launch_bounds__(512,2): VGPR cap 256 (R5 lesson).
__global__ __launch_bounds__(512, 2) void tail_kernel(
    const f16* __restrict__ A, const f16* __restrict__ WpR,
    const f16* __restrict__ W1R, const f16* __restrict__ W2R,
    const float* __restrict__ bp, const float* __restrict__ b1, const float* __restrict__ b2,
    const float* __restrict__ x, const float* __restrict__ g2, const float* __restrict__ be2,
    float* __restrict__ out)
{
  __shared__ __align__(16) f16 rowbuf[12*64*32];   // 49152B: A / h2 / mid
  __shared__ float lnred[2][64][4];
  __shared__ float lnmv[2][64];

  const int tid = threadIdx.x;
  const int lane = tid & 63, w = tid >> 6;
  const int wm = w >> 2, wn = w & 3;
  const int q = lane >> 4, c15 = lane & 15;
  const long row0 = (long)blockIdx.x * 64;

  // A-full staging offsets (16B chunks; XOR-swizzled k-groups) [R8-proven]
  long offA[6];
#pragma unroll
  for (int i = 0; i < 6; i++) {
    int cb = i*512 + tid;
    int kc = cb >> 8, c2 = cb & 255;
    int rA = c2 >> 2, pA = c2 & 3, gA = pA ^ ((rA >> 1) & 3);
    offA[i] = (row0 + rA)*384 + kc*32 + gA*8;
  }

  floatx4 acc[2][6] = {};

  // barrier-free GEMM over full K (12 x 32): A from rowbuf, B from L2
#define T_GEMM(WR) do { \
    _Pragma("unroll") \
    for (int kg = 0; kg < 12; kg++) { \
      half8 af[2]; \
      _Pragma("unroll") \
      for (int mi = 0; mi < 2; mi++) { \
        int r = wm*32 + mi*16 + c15; \
        int ph = q ^ ((r >> 1) & 3); \
        af[mi] = *(const half8*)(&rowbuf[kg*2048 + r*32 + ph*8]); \
      } \
      half8 bf[6]; \
      _Pragma("unroll") \
      for (int ni = 0; ni < 6; ni++) \
        bf[ni] = *(const half8*)((WR) + (size_t)(kg*24 + wn*6 + ni)*512 + lane*8); \
      _Pragma("unroll") \
      for (int mi = 0; mi < 2; mi++) \
        _Pragma("unroll") \
        for (int ni = 0; ni < 6; ni++) \
          acc[mi][ni] = __builtin_amdgcn_mfma_f32_16x16x32_f16(af[mi], bf[ni], acc[mi][ni], 0, 0, 0); \
    } \
  } while (0)

  // ---- stage A + prefetch x residual (latency hides under phase a) ----
#pragma unroll
  for (int i = 0; i < 6; i++)
    g2lds16(A + offA[i], (char*)rowbuf + (size_t)(i*512 + w*64)*16);
  float xv[2][6][4];
#pragma unroll
  for (int mi = 0; mi < 2; mi++)
#pragma unroll
    for (int rr = 0; rr < 4; rr++) {
      long row = row0 + wm*32 + mi*16 + q*4 + rr;
#pragma unroll
      for (int ni = 0; ni < 6; ni++)
        xv[mi][ni][rr] = x[row*384 + wn*96 + ni*16 + c15];
    }
  __syncthreads();            // [1] A staged

  // ================= phase a: x2 = x + A@Wp + bp ; h2 = LN2(x2) =================
  T_GEMM(WpR);

  float vals[2][6][4];
  {
    float colb[6], cg[6], cb2[6];
#pragma unroll
    for (int ni = 0; ni < 6; ni++) {
      int col = wn*96 + ni*16 + c15;
      colb[ni] = bp[col]; cg[ni] = g2[col]; cb2[ni] = be2[col];
    }
#pragma unroll
    for (int mi = 0; mi < 2; mi++)
#pragma unroll
      for (int rr = 0; rr < 4; rr++)
#pragma unroll
        for (int ni = 0; ni < 6; ni++)
          vals[mi][ni][rr] = acc[mi][ni][rr] + colb[ni] + xv[mi][ni][rr];
#pragma unroll
    for (int mi = 0; mi < 2; mi++) {
#pragma unroll
      for (int rr = 0; rr < 4; rr++) {
        float s = 0.f, s2 = 0.f;
#pragma unroll
        for (int ni = 0; ni < 6; ni++) { float v = vals[mi][ni][rr]; s += v; s2 += v*v; }
        s  += __shfl_xor(s, 1);  s  += __shfl_xor(s, 2);  s  += __shfl_xor(s, 4);  s  += __shfl_xor(s, 8);
        s2 += __shfl_xor(s2, 1); s2 += __shfl_xor(s2, 2); s2 += __shfl_xor(s2, 4); s2 += __shfl_xor(s2, 8);
        if (c15 == 0) {
          int lr = wm*32 + mi*16 + q*4 + rr;
          lnred[0][lr][wn] = s;
          lnred[1][lr][wn] = s2;
        }
      }
    }
    __syncthreads();          // [2] lnred ready; all phase-a rowbuf reads done
    if (tid < 64) {
      float s = 0.f, s2 = 0.f;
#pragma unroll
      for (int j = 0; j < 4; j++) { s += lnred[0][tid][j]; s2 += lnred[1][tid][j]; }
      float mu = s * (1.f/384.f);
      float var = s2 * (1.f/384.f) - mu*mu;
      lnmv[0][tid] = mu;
      lnmv[1][tid] = rsqrtf(var + 1e-5f);
    }
    __syncthreads();          // [3] lnmv ready
    // normalize -> h2 into rowbuf (staged-A swizzled layout)
#pragma unroll
    for (int mi = 0; mi < 2; mi++) {
#pragma unroll
      for (int rr = 0; rr < 4; rr++) {
        int lr = wm*32 + mi*16 + q*4 + rr;
        float mu = lnmv[0][lr], rs = lnmv[1][lr];
        int s_ = (lr >> 1) & 3;
#pragma unroll
        for (int ni = 0; ni < 6; ni++) {
          int cc = wn*96 + ni*16 + c15;
          float hv = (vals[mi][ni][rr] - mu)*rs*cg[ni] + cb2[ni];
          int chunk = cc >> 5, kk2 = cc & 31;
          int pos = ((kk2 >> 3) ^ s_)*8 + (kk2 & 7);
          rowbuf[chunk*2048 + lr*32 + pos] = (f16)hv;
        }
      }
    }
  }
  __syncthreads();            // [4] h2 published

  // ================= phase b: mid = relu(h2 @ W1 + b1) =================
#pragma unroll
  for (int mi = 0; mi < 2; mi++)
#pragma unroll
    for (int ni = 0; ni < 6; ni++)
      acc[mi][ni] = floatx4{0.f, 0.f, 0.f, 0.f};
  T_GEMM(W1R);
  __syncthreads();            // [5] all h2 reads done before rowbuf overwrite
  {
    float colb[6];
#pragma unroll
    for (int ni = 0; ni < 6; ni++) colb[ni] = b1[wn*96 + ni*16 + c15];
#pragma unroll
    for (int mi = 0; mi < 2; mi++) {
#pragma unroll
      for (int rr = 0; rr < 4; rr++) {
        int lr = wm*32 + mi*16 + q*4 + rr;
        int s_ = (lr >> 1) & 3;
#pragma unroll
        for (int ni = 0; ni < 6; ni++) {
          int cc = wn*96 + ni*16 + c15;
          float v = acc[mi][ni][rr] + colb[ni];
          v = v > 0.f ? v : 0.f;
          int chunk = cc >> 5, kk2 = cc & 31;
          int pos = ((kk2 >> 3) ^ s_)*8 + (kk2 & 7);
          rowbuf[chunk*2048 + lr*32 + pos] = (f16)v;
        }
      }
    }
  }
  __syncthreads();            // [6] mid published

  // ================= phase c: out = x2 + mid @ W2 + b2 =================
#pragma unroll
  for (int mi = 0; mi < 2; mi++)
#pragma unroll
    for (int ni = 0; ni < 6; ni++)
      acc[mi][ni] = floatx4{0.f, 0.f, 0.f, 0.f};
  T_GEMM(W2R);
  {
    float colb[6];
#pragma unroll
    for (int ni = 0; ni < 6; ni++) colb[ni] = b2[wn*96 + ni*16 + c15];
#pragma unroll
    for (int mi = 0; mi < 2; mi++) {
#pragma unroll
      for (int rr = 0; rr < 4; rr++) {
        long row = row0 + wm*32 + mi*16 + q*4 + rr;
#pragma unroll
        for (int ni = 0; ni < 6; ni++) {
          int col = wn*96 + ni*16 + c15;
          out[row*384 + col] = acc[mi][ni][rr] + colb[ni] + vals[mi][ni][rr];
        }
      }
    }
  }
#undef T_GEMM
}

extern "C" void kernel_launch(void* const* d_in, const int* in_sizes, int n_in,
                              void* d_out, int out_size, void* d_ws, size_t ws_size,
                              hipStream_t stream) {
  const float* x   = (const float*)d_in[0];
  const float* Wq  = (const float*)d_in[1];
  const float* bq  = (const float*)d_in[2];
  const float* Wk  = (const float*)d_in[3];
  const float* bk  = (const float*)d_in[4];
  const float* Wv  = (const float*)d_in[5];
  const float* bv  = (const float*)d_in[6];
  const float* Wp  = (const float*)d_in[7];
  const float* bp  = (const float*)d_in[8];
  const float* W1  = (const float*)d_in[9];
  const float* b1  = (const float*)d_in[10];
  const float* W2  = (const float*)d_in[11];
  const float* b2  = (const float*)d_in[12];
  const float* g1  = (const float*)d_in[13];
  const float* be1 = (const float*)d_in[14];
  const float* g2  = (const float*)d_in[15];
  const float* be2 = (const float*)d_in[16];

  char* ws = (char*)d_ws;
  size_t off = 0;
  auto alloc = [&](size_t bytes) -> void* {
    void* p = ws + off;
    off += (bytes + 255) & ~(size_t)255;
    return p;
  };
  f16*   Wqkv_t = (f16*)  alloc(1152*384*sizeof(f16));
  f16*   Wp_t   = (f16*)  alloc(384*384*sizeof(f16));   // fragment-major (R9)
  f16*   W1_t   = (f16*)  alloc(384*384*sizeof(f16));   // fragment-major (R9)
  f16*   W2_t   = (f16*)  alloc(384*384*sizeof(f16));   // fragment-major (R9)
  float* bqkv   = (float*)alloc(1152*sizeof(float));
  f16*   h      = (f16*)  alloc((size_t)NROWS*384*sizeof(f16));
  f16*   qkv    = (f16*)  alloc((size_t)NROWS*1152*sizeof(f16));
  f16*   attnb  = (f16*)  alloc((size_t)NROWS*384*sizeof(f16));

  // 1. fused: weight repack + LN1
  prep_ln_kernel<<<217 + NROWS/4, 256, 0, stream>>>(Wq, Wk, Wv, bq, bk, bv, Wp, W1, W2,
                                                    Wqkv_t, Wp_t, W1_t, W2_t, bqkv,
                                                    x, g1, be1, h);
  // 2. QKV: qkv[16384,1152] = h @ Wqkv + bqkv (f16 out)
  gemm_qkv_kernel<<<dim3(128, 9), 256, 0, stream>>>(h, Wqkv_t, bqkv, qkv, 1152);
  // 3. attention: 768 blocks x 512 threads (2 q-tiles per block)
  attn_kernel<<<B_*H_*2, 512, 0, stream>>>(qkv, attnb);
  // 4. fused tail: proj + residual + LN2 + FF1 + FF2 (barrier-free K-loops)
  tail_kernel<<<NROWS/64, 512, 0, stream>>>(attnb, Wp_t, W1_t, W2_t, bp, b1, b2,
                                            x, g2, be2, (float*)d_out);
}